// Round 1
// baseline (555.034 us; speedup 1.0000x reference)
//
#include <hip/hip_runtime.h>
#include <hip/hip_fp8.h>

// ---------------------------------------------------------------------------
// LightGCN on MI355X (gfx950).  R12 = R11 resubmitted verbatim (prior bench
// run died to an infra error: "MI355X container failed twice"; no counters).
// R10: 591 us; 3x k_spmm_8 @83.5 us. Lesson: SpMM cost ~ random line
// TRANSACTIONS (4M/layer), not bytes (fp8 vs f16 nearly identical).
// R11 cuts transactions structurally:
//  (1) layer 3 computed only at the 3*B batch rows (y3 feeds nothing else):
//      320K gathers instead of 4M -> fused k_spmm_b (~10 us vs ~90 us).
//  (2) layers 1-2 split into bipartite phases (dst-items then dst-users):
//      each phase's source sub-table (6.4 / 12.8 MB) is far more L2-resident
//      than the mixed 19.2 MB working set.
// CSR build (bucket counting sort), prep, gathers, loss unchanged from R10.
// Output: dual-pattern word (b<<16)|b, b = bf16 bits of the loss.
// ---------------------------------------------------------------------------

#define CDIV(a, b) (((a) + (b) - 1) / (b))

typedef __attribute__((ext_vector_type(8))) unsigned char uchar8;

__device__ __forceinline__ float fp8tof(unsigned char b) {
    __hip_fp8_e4m3 h; h.__x = (__hip_fp8_storage_t)b;
    return (float)h;
}
__device__ __forceinline__ unsigned char ftofp8(float f) {
    __hip_fp8_e4m3 h(f);
    return (unsigned char)h.__x;
}

__device__ __forceinline__ unsigned int dualbits(float f) {
    union { float f; unsigned int u; } c;
    c.f = f;
    unsigned int r = c.u + 0x7FFFu + ((c.u >> 16) & 1u);
    unsigned int b = r >> 16;
    return (b << 16) | b;
}

// harness template symbol — kept (proven-working config)
__global__ void LightGCN_67757404061704_kernel() {}

__global__ void k_mark(unsigned int* __restrict__ out, float v) {
    if (threadIdx.x == 0 && blockIdx.x == 0) out[0] = dualbits(v);
}

__global__ void k_zero_i32(int* __restrict__ p, int n) {
    int t = blockIdx.x * blockDim.x + threadIdx.x;
    if (t < n) p[t] = 0;
}

__global__ void k_zero_f32(float* __restrict__ p, int n) {
    int t = blockIdx.x * blockDim.x + threadIdx.x;
    if (t < n) p[t] = 0.0f;
}

// ============================ bucket CSR build (R9, verbatim) ==============
#define BSHIFT 10
#define BNODES 1024
#define EPB_H 16384
#define EPB_A 8192

__global__ void k_bhist(const int* __restrict__ dst, int* __restrict__ bsize,
                        int E, int NB) {
    __shared__ int h[512];
    for (int i = threadIdx.x; i < NB; i += blockDim.x) h[i] = 0;
    __syncthreads();
    int lo = blockIdx.x * EPB_H;
    int hi = lo + EPB_H; if (hi > E) hi = E;
    for (int k = lo + threadIdx.x; k < hi; k += blockDim.x)
        atomicAdd(&h[dst[k] >> BSHIFT], 1);
    __syncthreads();
    for (int i = threadIdx.x; i < NB; i += blockDim.x)
        if (h[i]) atomicAdd(&bsize[i], h[i]);
}

__global__ void k_bscan(const int* __restrict__ bsize, int* __restrict__ bstart,
                        int* __restrict__ bcur, int NB, int E,
                        int* __restrict__ offs, int N) {
    if (threadIdx.x == 0 && blockIdx.x == 0) {
        int run = 0;
        for (int i = 0; i < NB; i++) {
            bstart[i] = run; bcur[i] = run; run += bsize[i];
        }
        bstart[NB] = run;
        offs[N] = E;
    }
}

__global__ void k_binA(const int* __restrict__ src, const int* __restrict__ dst,
                       int* __restrict__ bcur, unsigned int* __restrict__ staging,
                       int E, int NB) {
    __shared__ int h[512];
    __shared__ int base_s[512];
    for (int i = threadIdx.x; i < NB; i += blockDim.x) h[i] = 0;
    __syncthreads();
    int lo = blockIdx.x * EPB_A;
    int hi = lo + EPB_A; if (hi > E) hi = E;
    for (int k = lo + threadIdx.x; k < hi; k += blockDim.x)
        atomicAdd(&h[dst[k] >> BSHIFT], 1);
    __syncthreads();
    for (int i = threadIdx.x; i < NB; i += blockDim.x) {
        int c = h[i];
        base_s[i] = c ? atomicAdd(&bcur[i], c) : 0;
        h[i] = 0;
    }
    __syncthreads();
    for (int k = lo + threadIdx.x; k < hi; k += blockDim.x) {
        int d = dst[k];
        int bkt = d >> BSHIFT;
        int p = base_s[bkt] + atomicAdd(&h[bkt], 1);
        staging[p] = (unsigned int)src[k] |
                     ((unsigned int)(d & (BNODES - 1)) << 19);
    }
}

__global__ void k_binB(const unsigned int* __restrict__ staging,
                       const int* __restrict__ bstart,
                       int* __restrict__ offs, int* __restrict__ edges, int N) {
    int b = blockIdx.x;
    int node0 = b << BSHIFT;
    int nn = N - node0; if (nn > BNODES) nn = BNODES;
    __shared__ int dcnt[BNODES];
    __shared__ int loffs[BNODES];
    __shared__ int fill[BNODES];
    __shared__ int ts[256];
    int tid = threadIdx.x;
    for (int i = tid; i < BNODES; i += 256) { dcnt[i] = 0; fill[i] = 0; }
    __syncthreads();
    int s0 = bstart[b], s1 = bstart[b + 1];
    for (int k = s0 + tid; k < s1; k += 256)
        atomicAdd(&dcnt[staging[k] >> 19], 1);
    __syncthreads();
    int base4 = tid * 4;
    int a0 = dcnt[base4], a1 = dcnt[base4 + 1], a2 = dcnt[base4 + 2], a3 = dcnt[base4 + 3];
    int tsum = a0 + a1 + a2 + a3;
    ts[tid] = tsum; __syncthreads();
    for (int off = 1; off < 256; off <<= 1) {
        int x = (tid >= off) ? ts[tid - off] : 0;
        __syncthreads();
        ts[tid] += x;
        __syncthreads();
    }
    int excl = ts[tid] - tsum;
    loffs[base4]     = excl;
    loffs[base4 + 1] = excl + a0;
    loffs[base4 + 2] = excl + a0 + a1;
    loffs[base4 + 3] = excl + a0 + a1 + a2;
    __syncthreads();
    for (int i = tid; i < nn; i += 256) offs[node0 + i] = s0 + loffs[i];
    for (int k = s0 + tid; k < s1; k += 256) {
        unsigned int r = staging[k];
        int dl = r >> 19;
        int p = s0 + loffs[dl] + atomicAdd(&fill[dl], 1);
        edges[p] = (int)(r & 0x7FFFFu);
    }
}

// ------------------- fallback CSR build (NB > 512 only) --------------------
__global__ void k_hist(const int* __restrict__ dst, int* __restrict__ cnt, int E) {
    int t = blockIdx.x * blockDim.x + threadIdx.x;
    if (t < E) atomicAdd(&cnt[dst[t] + 1], 1);
}

__global__ void k_scan1(const int* __restrict__ data, int* __restrict__ partials, int M) {
    int tid = threadIdx.x;
    int base = blockIdx.x * 2048 + tid * 8;
    int s = 0;
#pragma unroll
    for (int j = 0; j < 8; j++) { int i = base + j; s += (i < M) ? data[i] : 0; }
    __shared__ int sm[256];
    sm[tid] = s; __syncthreads();
    for (int off = 128; off; off >>= 1) {
        if (tid < off) sm[tid] += sm[tid + off];
        __syncthreads();
    }
    if (tid == 0) partials[blockIdx.x] = sm[0];
}

__global__ void k_scan2(int* __restrict__ partials, int nb) {
    if (threadIdx.x == 0 && blockIdx.x == 0) {
        int run = 0;
        for (int b = 0; b < nb; b++) { int v = partials[b]; partials[b] = run; run += v; }
    }
}

__global__ void k_scan3(int* __restrict__ data, const int* __restrict__ partials, int M) {
    int tid = threadIdx.x;
    int base = blockIdx.x * 2048 + tid * 8;
    int v[8]; int s = 0;
#pragma unroll
    for (int j = 0; j < 8; j++) { int i = base + j; v[j] = (i < M) ? data[i] : 0; s += v[j]; }
    __shared__ int sm[256];
    sm[tid] = s; __syncthreads();
    for (int off = 1; off < 256; off <<= 1) {
        int x = (tid >= off) ? sm[tid - off] : 0;
        __syncthreads();
        sm[tid] += x;
        __syncthreads();
    }
    int run = sm[tid] - s + partials[blockIdx.x];
#pragma unroll
    for (int j = 0; j < 8; j++) {
        int i = base + j;
        run += v[j];
        if (i < M) data[i] = run;
    }
}

__global__ void k_copy_i32(const int* __restrict__ a, int* __restrict__ b, int n) {
    int t = blockIdx.x * blockDim.x + threadIdx.x;
    if (t < n) b[t] = a[t];
}

__global__ void k_scatter(const int* __restrict__ src, const int* __restrict__ dst,
                          int* __restrict__ fillpos, int* __restrict__ esrt, int E) {
    int t = blockIdx.x * blockDim.x + threadIdx.x;
    if (t >= E) return;
    int d = dst[t];
    int p = atomicAdd(&fillpos[d], 1);
    esrt[p] = src[t];
}

// ========================= propagation (fp8 staged) ========================
#define SCALE0 32.0f
#define RENORM 4.0f

__global__ void k_prep(const float4* __restrict__ ue4, const float4* __restrict__ ie4,
                       const int* __restrict__ offs, uchar8* __restrict__ z0,
                       int N, int nu) {
    int t = blockIdx.x * blockDim.x + threadIdx.x;
    int node = t >> 3, lane = t & 7;
    if (node >= N) return;
    int deg = offs[node + 1] - offs[node];
    if (deg < 1) deg = 1;
    float s = SCALE0 * rsqrtf((float)deg);
    const float4* base = (node < nu) ? (ue4 + (size_t)node * 16)
                                     : (ie4 + (size_t)(node - nu) * 16);
    float4 a = base[lane * 2], b = base[lane * 2 + 1];
    uchar8 o;
    o[0] = ftofp8(a.x * s); o[1] = ftofp8(a.y * s);
    o[2] = ftofp8(a.z * s); o[3] = ftofp8(a.w * s);
    o[4] = ftofp8(b.x * s); o[5] = ftofp8(b.y * s);
    o[6] = ftofp8(b.z * s); o[7] = ftofp8(b.w * s);
    z0[(size_t)node * 8 + lane] = o;
}

// full SpMM over dst range [node0, node1): z_{l+1}[d] = (RENORM/deg)*sum z_l[s]
__global__ void k_spmm_8(const uchar8* __restrict__ zin, uchar8* __restrict__ zout,
                         const int* __restrict__ offs, const int* __restrict__ esrt,
                         int node0, int node1) {
    int t = blockIdx.x * blockDim.x + threadIdx.x;
    int node = node0 + (t >> 3), lane = t & 7;
    if (node >= node1) return;
    int beg = offs[node], end = offs[node + 1];
    float acc[8] = {0.f, 0.f, 0.f, 0.f, 0.f, 0.f, 0.f, 0.f};
    for (int k = beg; k < end; k++) {
        int s = esrt[k];
        uchar8 z = zin[(size_t)s * 8 + lane];
#pragma unroll
        for (int i = 0; i < 8; i++) acc[i] += fp8tof(z[i]);
    }
    int deg = end - beg;
    float scale = RENORM / (float)(deg < 1 ? 1 : deg);
    uchar8 o;
#pragma unroll
    for (int i = 0; i < 8; i++) o[i] = ftofp8(acc[i] * scale);
    zout[(size_t)node * 8 + lane] = o;
}

// layer-3 fused: compute y3 only at batch rows, accumulate straight into accb.
// contribution = sqrt(deg)*invS3 * (RENORM/deg) * sum_{s in N(d)} z2[s]
__global__ void k_spmm_b(const uchar8* __restrict__ z2, float4* __restrict__ accb,
                         const int* __restrict__ users, const int* __restrict__ pos,
                         const int* __restrict__ neg, const int* __restrict__ offs,
                         const int* __restrict__ esrt, int B, int nu, float invS3) {
    int t = blockIdx.x * blockDim.x + threadIdx.x;
    int r = t >> 3, lane = t & 7;
    if (r >= 3 * B) return;
    int node;
    if (r < B) node = users[r];
    else if (r < 2 * B) node = nu + pos[r - B];
    else node = nu + neg[r - 2 * B];
    int beg = offs[node], end = offs[node + 1];
    float acc[8] = {0.f, 0.f, 0.f, 0.f, 0.f, 0.f, 0.f, 0.f};
    for (int k = beg; k < end; k++) {
        int s = esrt[k];
        uchar8 z = z2[(size_t)s * 8 + lane];
#pragma unroll
        for (int i = 0; i < 8; i++) acc[i] += fp8tof(z[i]);
    }
    int deg = end - beg;
    if (deg < 1) deg = 1;
    float scale = sqrtf((float)deg) * invS3 * RENORM / (float)deg;
    size_t ai = (size_t)r * 16 + lane * 2;
    float4 a = accb[ai], b = accb[ai + 1];
    a.x += acc[0] * scale; a.y += acc[1] * scale;
    a.z += acc[2] * scale; a.w += acc[3] * scale;
    b.x += acc[4] * scale; b.y += acc[5] * scale;
    b.z += acc[6] * scale; b.w += acc[7] * scale;
    accb[ai] = a; accb[ai + 1] = b;
}

__global__ void k_gather_init(const float4* __restrict__ ue4, const float4* __restrict__ ie4,
                              float4* __restrict__ accb,
                              const int* __restrict__ users, const int* __restrict__ pos,
                              const int* __restrict__ neg, int B, int nu) {
    int t = blockIdx.x * blockDim.x + threadIdx.x;
    int r = t >> 4, lane = t & 15;
    if (r >= 3 * B) return;
    int node;
    if (r < B) node = users[r];
    else if (r < 2 * B) node = nu + pos[r - B];
    else node = nu + neg[r - 2 * B];
    accb[(size_t)r * 16 + lane] = (node < nu) ? ue4[(size_t)node * 16 + lane]
                                              : ie4[(size_t)(node - nu) * 16 + lane];
}

__global__ void k_gather_acc_8(const uchar8* __restrict__ z, float4* __restrict__ accb,
                               const int* __restrict__ users, const int* __restrict__ pos,
                               const int* __restrict__ neg, const int* __restrict__ offs,
                               int B, int nu, float invS) {
    int t = blockIdx.x * blockDim.x + threadIdx.x;
    int r = t >> 3, lane = t & 7;
    if (r >= 3 * B) return;
    int node;
    if (r < B) node = users[r];
    else if (r < 2 * B) node = nu + pos[r - B];
    else node = nu + neg[r - 2 * B];
    int deg = offs[node + 1] - offs[node];
    if (deg < 1) deg = 1;
    float s = sqrtf((float)deg) * invS;
    uchar8 h = z[(size_t)node * 8 + lane];
    size_t ai = (size_t)r * 16 + lane * 2;
    float4 a = accb[ai], b = accb[ai + 1];
    a.x += fp8tof(h[0]) * s; a.y += fp8tof(h[1]) * s;
    a.z += fp8tof(h[2]) * s; a.w += fp8tof(h[3]) * s;
    b.x += fp8tof(h[4]) * s; b.y += fp8tof(h[5]) * s;
    b.z += fp8tof(h[6]) * s; b.w += fp8tof(h[7]) * s;
    accb[ai] = a; accb[ai + 1] = b;
}

__global__ void k_loss(const float* __restrict__ accb, float* __restrict__ lsum, int B) {
    int tid = threadIdx.x;
    int wave = tid >> 6, lane = tid & 63;
    int r = blockIdx.x * 4 + wave;
    float u  = accb[(size_t)r * 64 + lane] * 0.25f;
    float p  = accb[(size_t)(B + r) * 64 + lane] * 0.25f;
    float nv = accb[(size_t)(2 * B + r) * 64 + lane] * 0.25f;
    float pd = u * p, nd = u * nv;
    for (int off = 32; off; off >>= 1) {
        pd += __shfl_down(pd, off, 64);
        nd += __shfl_down(nd, off, 64);
    }
    __shared__ float sm[4];
    if (lane == 0) {
        float x = nd - pd;
        sm[wave] = fmaxf(x, 0.f) + log1pf(expf(-fabsf(x)));
    }
    __syncthreads();
    if (tid == 0) atomicAdd(lsum, sm[0] + sm[1] + sm[2] + sm[3]);
}

__global__ void k_final(const float* __restrict__ lsum, unsigned int* __restrict__ out,
                        float invB) {
    if (threadIdx.x == 0 && blockIdx.x == 0) {
        out[0] = dualbits(lsum[0] * invB);
    }
}

// ---------------------------------------------------------------------------
extern "C" void kernel_launch(void* const* d_in, const int* in_sizes, int n_in,
                              void* d_out, int out_size, void* d_ws, size_t ws_size,
                              hipStream_t stream) {
    const float* ue   = (const float*)d_in[0];
    const float* ie   = (const float*)d_in[1];
    const int*   esrc = (const int*)d_in[2];
    const int*   edst = (const int*)d_in[3];
    const int*   usr  = (const int*)d_in[5];
    const int*   pos  = (const int*)d_in[6];
    const int*   neg  = (const int*)d_in[7];

    const int D  = 64;
    const int nu = in_sizes[0] / D;        // 100000
    const int N  = nu + in_sizes[1] / D;   // 300000
    const int E  = in_sizes[2];            // 4000000
    const int B  = in_sizes[5];            // 8192
    (void)n_in; (void)out_size;

    unsigned int* out = (unsigned int*)d_out;

    LightGCN_67757404061704_kernel<<<1, 64, 0, stream>>>();
    k_mark<<<1, 64, 0, stream>>>(out, 5.0f);

    const int NB = CDIV(N, BNODES);        // 293

    auto align16 = [](size_t x) { return (x + 15) & ~(size_t)15; };
    size_t need = 0;
    need += 2 * align16((size_t)N * D);                       // z0, z1 (fp8)
    need += align16((size_t)3 * B * D * sizeof(float));       // accb
    need += align16(sizeof(float));                           // lsum
    need += align16((size_t)(N + 1) * sizeof(int));           // offs
    need += align16((size_t)N * sizeof(int));                 // fillpos (fallback)
    need += align16((size_t)2048 * sizeof(int));              // partials (fallback)
    need += align16((size_t)512 * sizeof(int));               // bsize
    need += align16((size_t)513 * sizeof(int));               // bstart
    need += align16((size_t)512 * sizeof(int));               // bcur
    need += align16((size_t)E * sizeof(unsigned int));        // staging
    need += align16((size_t)E * sizeof(int));                 // esrt
    need += 1024;
    if (d_ws == nullptr || ws_size < need) {
        k_mark<<<1, 64, 0, stream>>>(out, 150.0f);
        return;
    }

    char* w = (char*)d_ws;
    uchar8* z0 = (uchar8*)w;  w += align16((size_t)N * D);
    uchar8* z1 = (uchar8*)w;  w += align16((size_t)N * D);
    float* accb = (float*)w;  w += align16((size_t)3 * B * D * sizeof(float));
    float* lsum = (float*)w;  w += align16(sizeof(float));
    int* offs     = (int*)w;  w += align16((size_t)(N + 1) * sizeof(int));
    int* fillpos  = (int*)w;  w += align16((size_t)N * sizeof(int));
    int* partials = (int*)w;  w += align16((size_t)2048 * sizeof(int));
    int* bsize    = (int*)w;  w += align16((size_t)512 * sizeof(int));
    int* bstart   = (int*)w;  w += align16((size_t)513 * sizeof(int));
    int* bcur     = (int*)w;  w += align16((size_t)512 * sizeof(int));
    unsigned int* staging = (unsigned int*)w; w += align16((size_t)E * sizeof(unsigned int));
    int* esrt     = (int*)w;

    const int BS = 256;

    // --- CSR build ---
    if (NB <= 512 && N < (1 << 19)) {
        k_zero_i32<<<CDIV(512, BS), BS, 0, stream>>>(bsize, 512);
        k_bhist<<<CDIV(E, EPB_H), BS, 0, stream>>>(edst, bsize, E, NB);
        k_bscan<<<1, 64, 0, stream>>>(bsize, bstart, bcur, NB, E, offs, N);
        k_binA<<<CDIV(E, EPB_A), BS, 0, stream>>>(esrc, edst, bcur, staging, E, NB);
        k_binB<<<NB, 256, 0, stream>>>(staging, bstart, offs, esrt, N);
    } else {
        k_zero_i32<<<CDIV(N + 1, BS), BS, 0, stream>>>(offs, N + 1);
        k_hist<<<CDIV(E, BS), BS, 0, stream>>>(edst, offs, E);
        int M = N + 1;
        int nb = CDIV(M, 2048);
        k_scan1<<<nb, BS, 0, stream>>>(offs, partials, M);
        k_scan2<<<1, 64, 0, stream>>>(partials, nb);
        k_scan3<<<nb, BS, 0, stream>>>(offs, partials, M);
        k_copy_i32<<<CDIV(N, BS), BS, 0, stream>>>(offs, fillpos, N);
        k_scatter<<<CDIV(E, BS), BS, 0, stream>>>(esrc, edst, fillpos, esrt, E);
    }

    // --- stage z0 (fp8, scaled) ---
    int pthreads = N * 8;
    k_prep<<<CDIV(pthreads, BS), BS, 0, stream>>>((const float4*)ue, (const float4*)ie,
                                                  offs, z0, N, nu);

    // --- batch acc: layer 0 from f32 inputs ---
    int g16 = 3 * B * 16;
    int g8  = 3 * B * 8;
    k_gather_init<<<CDIV(g16, BS), BS, 0, stream>>>((const float4*)ue, (const float4*)ie,
                                                    (float4*)accb, usr, pos, neg, B, nu);

    // --- layers 1-2: full SpMM, bipartite phase split ---
    int th_items = (N - nu) * 8;   // dst = items, src = users (6.4 MB table)
    int th_users = nu * 8;         // dst = users, src = items (12.8 MB table)
    uchar8* a = z0; uchar8* b = z1;
    float invS = 1.0f / SCALE0;
    for (int layer = 0; layer < 2; layer++) {
        k_spmm_8<<<CDIV(th_items, BS), BS, 0, stream>>>(a, b, offs, esrt, nu, N);
        k_spmm_8<<<CDIV(th_users, BS), BS, 0, stream>>>(a, b, offs, esrt, 0, nu);
        invS /= RENORM;
        k_gather_acc_8<<<CDIV(g8, BS), BS, 0, stream>>>(b, (float4*)accb,
                                                        usr, pos, neg, offs, B, nu, invS);
        uchar8* tmp = a; a = b; b = tmp;
    }

    // --- layer 3: batch rows only, fused into accb ---
    k_spmm_b<<<CDIV(g8, BS), BS, 0, stream>>>(a, (float4*)accb, usr, pos, neg,
                                              offs, esrt, B, nu, invS / RENORM);

    // --- loss ---
    k_zero_f32<<<1, 64, 0, stream>>>(lsum, 1);
    k_loss<<<B / 4, BS, 0, stream>>>(accb, lsum, B);
    k_final<<<1, 64, 0, stream>>>(lsum, out, 1.0f / (float)B);
}

// Round 7
// 547.460 us; speedup vs baseline: 1.0138x; 1.0138x over previous
//
#include <hip/hip_runtime.h>
#include <hip/hip_fp8.h>

// ---------------------------------------------------------------------------
// LightGCN on MI355X (gfx950).  R18 = R13 resubmitted verbatim (R13..R17
// never ran: GPUAcquisitionTimeout x5; candidate still unmeasured).
// R12 (=R11): 555.0 us. rocprof: k_binA is #1 dispatch @58.7 us and is
// LATENCY-bound: 794 GB/s (10% peak), VALUBusy 3%, Occupancy 17% (489 blocks
// only). Whole CSR build chain is under-parallelized:
//   bhist 245 blocks, binA 489 blocks, binB 293 blocks@256t, bscan 1 thread.
// R13..R18: occupancy fixes only (SpMM untouched):
//  (1) EPB_A 8192->2048  (1954 blocks, ~30 waves/CU)
//  (2) EPB_H 16384->4096 (977 blocks)
//  (3) k_bscan: serial 1-thread loop -> 512-thread parallel scan
//  (4) k_binB: 256 -> 1024 threads/block (1 bucket/thread scan)
// Predicted: binA 58.7->~18 us (same bytes, >=2.2 TB/s), binB ~2x, total
// 555 -> ~450-480 us.
// Output: dual-pattern word (b<<16)|b, b = bf16 bits of the loss.
// ---------------------------------------------------------------------------

#define CDIV(a, b) (((a) + (b) - 1) / (b))

typedef __attribute__((ext_vector_type(8))) unsigned char uchar8;

__device__ __forceinline__ float fp8tof(unsigned char b) {
    __hip_fp8_e4m3 h; h.__x = (__hip_fp8_storage_t)b;
    return (float)h;
}
__device__ __forceinline__ unsigned char ftofp8(float f) {
    __hip_fp8_e4m3 h(f);
    return (unsigned char)h.__x;
}

__device__ __forceinline__ unsigned int dualbits(float f) {
    union { float f; unsigned int u; } c;
    c.f = f;
    unsigned int r = c.u + 0x7FFFu + ((c.u >> 16) & 1u);
    unsigned int b = r >> 16;
    return (b << 16) | b;
}

// harness template symbol — kept (proven-working config)
__global__ void LightGCN_67757404061704_kernel() {}

__global__ void k_mark(unsigned int* __restrict__ out, float v) {
    if (threadIdx.x == 0 && blockIdx.x == 0) out[0] = dualbits(v);
}

__global__ void k_zero_i32(int* __restrict__ p, int n) {
    int t = blockIdx.x * blockDim.x + threadIdx.x;
    if (t < n) p[t] = 0;
}

__global__ void k_zero_f32(float* __restrict__ p, int n) {
    int t = blockIdx.x * blockDim.x + threadIdx.x;
    if (t < n) p[t] = 0.0f;
}

// ============================ bucket CSR build =============================
#define BSHIFT 10
#define BNODES 1024
#define EPB_H 4096
#define EPB_A 2048

__global__ void k_bhist(const int* __restrict__ dst, int* __restrict__ bsize,
                        int E, int NB) {
    __shared__ int h[512];
    for (int i = threadIdx.x; i < NB; i += blockDim.x) h[i] = 0;
    __syncthreads();
    int lo = blockIdx.x * EPB_H;
    int hi = lo + EPB_H; if (hi > E) hi = E;
    for (int k = lo + threadIdx.x; k < hi; k += blockDim.x)
        atomicAdd(&h[dst[k] >> BSHIFT], 1);
    __syncthreads();
    for (int i = threadIdx.x; i < NB; i += blockDim.x)
        if (h[i]) atomicAdd(&bsize[i], h[i]);
}

// parallel exclusive scan over NB (<512) buckets; one 512-thread block.
__global__ void k_bscan(const int* __restrict__ bsize, int* __restrict__ bstart,
                        int* __restrict__ bcur, int NB, int E,
                        int* __restrict__ offs, int N) {
    __shared__ int sm[512];
    int tid = threadIdx.x;
    int v = (tid < NB) ? bsize[tid] : 0;
    sm[tid] = v;
    __syncthreads();
    for (int off = 1; off < 512; off <<= 1) {
        int x = (tid >= off) ? sm[tid - off] : 0;
        __syncthreads();
        sm[tid] += x;
        __syncthreads();
    }
    int excl = sm[tid] - v;
    if (tid <= NB) bstart[tid] = excl;   // tid==NB -> total == E
    if (tid < NB)  bcur[tid] = excl;
    if (tid == 0)  offs[N] = E;
}

__global__ void k_binA(const int* __restrict__ src, const int* __restrict__ dst,
                       int* __restrict__ bcur, unsigned int* __restrict__ staging,
                       int E, int NB) {
    __shared__ int h[512];
    __shared__ int base_s[512];
    for (int i = threadIdx.x; i < NB; i += blockDim.x) h[i] = 0;
    __syncthreads();
    int lo = blockIdx.x * EPB_A;
    int hi = lo + EPB_A; if (hi > E) hi = E;
    for (int k = lo + threadIdx.x; k < hi; k += blockDim.x)
        atomicAdd(&h[dst[k] >> BSHIFT], 1);
    __syncthreads();
    for (int i = threadIdx.x; i < NB; i += blockDim.x) {
        int c = h[i];
        base_s[i] = c ? atomicAdd(&bcur[i], c) : 0;
        h[i] = 0;
    }
    __syncthreads();
    for (int k = lo + threadIdx.x; k < hi; k += blockDim.x) {
        int d = dst[k];
        int bkt = d >> BSHIFT;
        int p = base_s[bkt] + atomicAdd(&h[bkt], 1);
        staging[p] = (unsigned int)src[k] |
                     ((unsigned int)(d & (BNODES - 1)) << 19);
    }
}

// 1024 threads: 1 bucket-local node per thread for count/scan phases.
__global__ void k_binB(const unsigned int* __restrict__ staging,
                       const int* __restrict__ bstart,
                       int* __restrict__ offs, int* __restrict__ edges, int N) {
    int b = blockIdx.x;
    int node0 = b << BSHIFT;
    int nn = N - node0; if (nn > BNODES) nn = BNODES;
    __shared__ int dcnt[BNODES];
    __shared__ int loffs[BNODES];
    __shared__ int fill[BNODES];
    int tid = threadIdx.x;              // 0..1023
    dcnt[tid] = 0; fill[tid] = 0;
    __syncthreads();
    int s0 = bstart[b], s1 = bstart[b + 1];
    for (int k = s0 + tid; k < s1; k += 1024)
        atomicAdd(&dcnt[staging[k] >> 19], 1);
    __syncthreads();
    int v = dcnt[tid];
    loffs[tid] = v;
    __syncthreads();
    for (int off = 1; off < 1024; off <<= 1) {
        int x = (tid >= off) ? loffs[tid - off] : 0;
        __syncthreads();
        loffs[tid] += x;
        __syncthreads();
    }
    int excl = loffs[tid] - v;
    __syncthreads();
    loffs[tid] = excl;
    __syncthreads();
    if (tid < nn) offs[node0 + tid] = s0 + excl;
    for (int k = s0 + tid; k < s1; k += 1024) {
        unsigned int r = staging[k];
        int dl = r >> 19;
        int p = s0 + loffs[dl] + atomicAdd(&fill[dl], 1);
        edges[p] = (int)(r & 0x7FFFFu);
    }
}

// ------------------- fallback CSR build (NB > 511 only) --------------------
__global__ void k_hist(const int* __restrict__ dst, int* __restrict__ cnt, int E) {
    int t = blockIdx.x * blockDim.x + threadIdx.x;
    if (t < E) atomicAdd(&cnt[dst[t] + 1], 1);
}

__global__ void k_scan1(const int* __restrict__ data, int* __restrict__ partials, int M) {
    int tid = threadIdx.x;
    int base = blockIdx.x * 2048 + tid * 8;
    int s = 0;
#pragma unroll
    for (int j = 0; j < 8; j++) { int i = base + j; s += (i < M) ? data[i] : 0; }
    __shared__ int sm[256];
    sm[tid] = s; __syncthreads();
    for (int off = 128; off; off >>= 1) {
        if (tid < off) sm[tid] += sm[tid + off];
        __syncthreads();
    }
    if (tid == 0) partials[blockIdx.x] = sm[0];
}

__global__ void k_scan2(int* __restrict__ partials, int nb) {
    if (threadIdx.x == 0 && blockIdx.x == 0) {
        int run = 0;
        for (int b = 0; b < nb; b++) { int v = partials[b]; partials[b] = run; run += v; }
    }
}

__global__ void k_scan3(int* __restrict__ data, const int* __restrict__ partials, int M) {
    int tid = threadIdx.x;
    int base = blockIdx.x * 2048 + tid * 8;
    int v[8]; int s = 0;
#pragma unroll
    for (int j = 0; j < 8; j++) { int i = base + j; v[j] = (i < M) ? data[i] : 0; s += v[j]; }
    __shared__ int sm[256];
    sm[tid] = s; __syncthreads();
    for (int off = 1; off < 256; off <<= 1) {
        int x = (tid >= off) ? sm[tid - off] : 0;
        __syncthreads();
        sm[tid] += x;
        __syncthreads();
    }
    int run = sm[tid] - s + partials[blockIdx.x];
#pragma unroll
    for (int j = 0; j < 8; j++) {
        int i = base + j;
        run += v[j];
        if (i < M) data[i] = run;
    }
}

__global__ void k_copy_i32(const int* __restrict__ a, int* __restrict__ b, int n) {
    int t = blockIdx.x * blockDim.x + threadIdx.x;
    if (t < n) b[t] = a[t];
}

__global__ void k_scatter(const int* __restrict__ src, const int* __restrict__ dst,
                          int* __restrict__ fillpos, int* __restrict__ esrt, int E) {
    int t = blockIdx.x * blockDim.x + threadIdx.x;
    if (t >= E) return;
    int d = dst[t];
    int p = atomicAdd(&fillpos[d], 1);
    esrt[p] = src[t];
}

// ========================= propagation (fp8 staged) ========================
#define SCALE0 32.0f
#define RENORM 4.0f

__global__ void k_prep(const float4* __restrict__ ue4, const float4* __restrict__ ie4,
                       const int* __restrict__ offs, uchar8* __restrict__ z0,
                       int N, int nu) {
    int t = blockIdx.x * blockDim.x + threadIdx.x;
    int node = t >> 3, lane = t & 7;
    if (node >= N) return;
    int deg = offs[node + 1] - offs[node];
    if (deg < 1) deg = 1;
    float s = SCALE0 * rsqrtf((float)deg);
    const float4* base = (node < nu) ? (ue4 + (size_t)node * 16)
                                     : (ie4 + (size_t)(node - nu) * 16);
    float4 a = base[lane * 2], b = base[lane * 2 + 1];
    uchar8 o;
    o[0] = ftofp8(a.x * s); o[1] = ftofp8(a.y * s);
    o[2] = ftofp8(a.z * s); o[3] = ftofp8(a.w * s);
    o[4] = ftofp8(b.x * s); o[5] = ftofp8(b.y * s);
    o[6] = ftofp8(b.z * s); o[7] = ftofp8(b.w * s);
    z0[(size_t)node * 8 + lane] = o;
}

// full SpMM over dst range [node0, node1): z_{l+1}[d] = (RENORM/deg)*sum z_l[s]
__global__ void k_spmm_8(const uchar8* __restrict__ zin, uchar8* __restrict__ zout,
                         const int* __restrict__ offs, const int* __restrict__ esrt,
                         int node0, int node1) {
    int t = blockIdx.x * blockDim.x + threadIdx.x;
    int node = node0 + (t >> 3), lane = t & 7;
    if (node >= node1) return;
    int beg = offs[node], end = offs[node + 1];
    float acc[8] = {0.f, 0.f, 0.f, 0.f, 0.f, 0.f, 0.f, 0.f};
    for (int k = beg; k < end; k++) {
        int s = esrt[k];
        uchar8 z = zin[(size_t)s * 8 + lane];
#pragma unroll
        for (int i = 0; i < 8; i++) acc[i] += fp8tof(z[i]);
    }
    int deg = end - beg;
    float scale = RENORM / (float)(deg < 1 ? 1 : deg);
    uchar8 o;
#pragma unroll
    for (int i = 0; i < 8; i++) o[i] = ftofp8(acc[i] * scale);
    zout[(size_t)node * 8 + lane] = o;
}

// layer-3 fused: compute y3 only at batch rows, accumulate straight into accb.
// contribution = sqrt(deg)*invS3 * (RENORM/deg) * sum_{s in N(d)} z2[s]
__global__ void k_spmm_b(const uchar8* __restrict__ z2, float4* __restrict__ accb,
                         const int* __restrict__ users, const int* __restrict__ pos,
                         const int* __restrict__ neg, const int* __restrict__ offs,
                         const int* __restrict__ esrt, int B, int nu, float invS3) {
    int t = blockIdx.x * blockDim.x + threadIdx.x;
    int r = t >> 3, lane = t & 7;
    if (r >= 3 * B) return;
    int node;
    if (r < B) node = users[r];
    else if (r < 2 * B) node = nu + pos[r - B];
    else node = nu + neg[r - 2 * B];
    int beg = offs[node], end = offs[node + 1];
    float acc[8] = {0.f, 0.f, 0.f, 0.f, 0.f, 0.f, 0.f, 0.f};
    for (int k = beg; k < end; k++) {
        int s = esrt[k];
        uchar8 z = z2[(size_t)s * 8 + lane];
#pragma unroll
        for (int i = 0; i < 8; i++) acc[i] += fp8tof(z[i]);
    }
    int deg = end - beg;
    if (deg < 1) deg = 1;
    float scale = sqrtf((float)deg) * invS3 * RENORM / (float)deg;
    size_t ai = (size_t)r * 16 + lane * 2;
    float4 a = accb[ai], b = accb[ai + 1];
    a.x += acc[0] * scale; a.y += acc[1] * scale;
    a.z += acc[2] * scale; a.w += acc[3] * scale;
    b.x += acc[4] * scale; b.y += acc[5] * scale;
    b.z += acc[6] * scale; b.w += acc[7] * scale;
    accb[ai] = a; accb[ai + 1] = b;
}

__global__ void k_gather_init(const float4* __restrict__ ue4, const float4* __restrict__ ie4,
                              float4* __restrict__ accb,
                              const int* __restrict__ users, const int* __restrict__ pos,
                              const int* __restrict__ neg, int B, int nu) {
    int t = blockIdx.x * blockDim.x + threadIdx.x;
    int r = t >> 4, lane = t & 15;
    if (r >= 3 * B) return;
    int node;
    if (r < B) node = users[r];
    else if (r < 2 * B) node = nu + pos[r - B];
    else node = nu + neg[r - 2 * B];
    accb[(size_t)r * 16 + lane] = (node < nu) ? ue4[(size_t)node * 16 + lane]
                                              : ie4[(size_t)(node - nu) * 16 + lane];
}

__global__ void k_gather_acc_8(const uchar8* __restrict__ z, float4* __restrict__ accb,
                               const int* __restrict__ users, const int* __restrict__ pos,
                               const int* __restrict__ neg, const int* __restrict__ offs,
                               int B, int nu, float invS) {
    int t = blockIdx.x * blockDim.x + threadIdx.x;
    int r = t >> 3, lane = t & 7;
    if (r >= 3 * B) return;
    int node;
    if (r < B) node = users[r];
    else if (r < 2 * B) node = nu + pos[r - B];
    else node = nu + neg[r - 2 * B];
    int deg = offs[node + 1] - offs[node];
    if (deg < 1) deg = 1;
    float s = sqrtf((float)deg) * invS;
    uchar8 h = z[(size_t)node * 8 + lane];
    size_t ai = (size_t)r * 16 + lane * 2;
    float4 a = accb[ai], b = accb[ai + 1];
    a.x += fp8tof(h[0]) * s; a.y += fp8tof(h[1]) * s;
    a.z += fp8tof(h[2]) * s; a.w += fp8tof(h[3]) * s;
    b.x += fp8tof(h[4]) * s; b.y += fp8tof(h[5]) * s;
    b.z += fp8tof(h[6]) * s; b.w += fp8tof(h[7]) * s;
    accb[ai] = a; accb[ai + 1] = b;
}

__global__ void k_loss(const float* __restrict__ accb, float* __restrict__ lsum, int B) {
    int tid = threadIdx.x;
    int wave = tid >> 6, lane = tid & 63;
    int r = blockIdx.x * 4 + wave;
    float u  = accb[(size_t)r * 64 + lane] * 0.25f;
    float p  = accb[(size_t)(B + r) * 64 + lane] * 0.25f;
    float nv = accb[(size_t)(2 * B + r) * 64 + lane] * 0.25f;
    float pd = u * p, nd = u * nv;
    for (int off = 32; off; off >>= 1) {
        pd += __shfl_down(pd, off, 64);
        nd += __shfl_down(nd, off, 64);
    }
    __shared__ float sm[4];
    if (lane == 0) {
        float x = nd - pd;
        sm[wave] = fmaxf(x, 0.f) + log1pf(expf(-fabsf(x)));
    }
    __syncthreads();
    if (tid == 0) atomicAdd(lsum, sm[0] + sm[1] + sm[2] + sm[3]);
}

__global__ void k_final(const float* __restrict__ lsum, unsigned int* __restrict__ out,
                        float invB) {
    if (threadIdx.x == 0 && blockIdx.x == 0) {
        out[0] = dualbits(lsum[0] * invB);
    }
}

// ---------------------------------------------------------------------------
extern "C" void kernel_launch(void* const* d_in, const int* in_sizes, int n_in,
                              void* d_out, int out_size, void* d_ws, size_t ws_size,
                              hipStream_t stream) {
    const float* ue   = (const float*)d_in[0];
    const float* ie   = (const float*)d_in[1];
    const int*   esrc = (const int*)d_in[2];
    const int*   edst = (const int*)d_in[3];
    const int*   usr  = (const int*)d_in[5];
    const int*   pos  = (const int*)d_in[6];
    const int*   neg  = (const int*)d_in[7];

    const int D  = 64;
    const int nu = in_sizes[0] / D;        // 100000
    const int N  = nu + in_sizes[1] / D;   // 300000
    const int E  = in_sizes[2];            // 4000000
    const int B  = in_sizes[5];            // 8192
    (void)n_in; (void)out_size;

    unsigned int* out = (unsigned int*)d_out;

    LightGCN_67757404061704_kernel<<<1, 64, 0, stream>>>();
    k_mark<<<1, 64, 0, stream>>>(out, 5.0f);

    const int NB = CDIV(N, BNODES);        // 293

    auto align16 = [](size_t x) { return (x + 15) & ~(size_t)15; };
    size_t need = 0;
    need += 2 * align16((size_t)N * D);                       // z0, z1 (fp8)
    need += align16((size_t)3 * B * D * sizeof(float));       // accb
    need += align16(sizeof(float));                           // lsum
    need += align16((size_t)(N + 1) * sizeof(int));           // offs
    need += align16((size_t)N * sizeof(int));                 // fillpos (fallback)
    need += align16((size_t)2048 * sizeof(int));              // partials (fallback)
    need += align16((size_t)512 * sizeof(int));               // bsize
    need += align16((size_t)513 * sizeof(int));               // bstart
    need += align16((size_t)512 * sizeof(int));               // bcur
    need += align16((size_t)E * sizeof(unsigned int));        // staging
    need += align16((size_t)E * sizeof(int));                 // esrt
    need += 1024;
    if (d_ws == nullptr || ws_size < need) {
        k_mark<<<1, 64, 0, stream>>>(out, 150.0f);
        return;
    }

    char* w = (char*)d_ws;
    uchar8* z0 = (uchar8*)w;  w += align16((size_t)N * D);
    uchar8* z1 = (uchar8*)w;  w += align16((size_t)N * D);
    float* accb = (float*)w;  w += align16((size_t)3 * B * D * sizeof(float));
    float* lsum = (float*)w;  w += align16(sizeof(float));
    int* offs     = (int*)w;  w += align16((size_t)(N + 1) * sizeof(int));
    int* fillpos  = (int*)w;  w += align16((size_t)N * sizeof(int));
    int* partials = (int*)w;  w += align16((size_t)2048 * sizeof(int));
    int* bsize    = (int*)w;  w += align16((size_t)512 * sizeof(int));
    int* bstart   = (int*)w;  w += align16((size_t)513 * sizeof(int));
    int* bcur     = (int*)w;  w += align16((size_t)512 * sizeof(int));
    unsigned int* staging = (unsigned int*)w; w += align16((size_t)E * sizeof(unsigned int));
    int* esrt     = (int*)w;

    const int BS = 256;

    // --- CSR build ---
    if (NB <= 511 && N < (1 << 19)) {
        k_zero_i32<<<CDIV(512, BS), BS, 0, stream>>>(bsize, 512);
        k_bhist<<<CDIV(E, EPB_H), BS, 0, stream>>>(edst, bsize, E, NB);
        k_bscan<<<1, 512, 0, stream>>>(bsize, bstart, bcur, NB, E, offs, N);
        k_binA<<<CDIV(E, EPB_A), BS, 0, stream>>>(esrc, edst, bcur, staging, E, NB);
        k_binB<<<NB, 1024, 0, stream>>>(staging, bstart, offs, esrt, N);
    } else {
        k_zero_i32<<<CDIV(N + 1, BS), BS, 0, stream>>>(offs, N + 1);
        k_hist<<<CDIV(E, BS), BS, 0, stream>>>(edst, offs, E);
        int M = N + 1;
        int nb = CDIV(M, 2048);
        k_scan1<<<nb, BS, 0, stream>>>(offs, partials, M);
        k_scan2<<<1, 64, 0, stream>>>(partials, nb);
        k_scan3<<<nb, BS, 0, stream>>>(offs, partials, M);
        k_copy_i32<<<CDIV(N, BS), BS, 0, stream>>>(offs, fillpos, N);
        k_scatter<<<CDIV(E, BS), BS, 0, stream>>>(esrc, edst, fillpos, esrt, E);
    }

    // --- stage z0 (fp8, scaled) ---
    int pthreads = N * 8;
    k_prep<<<CDIV(pthreads, BS), BS, 0, stream>>>((const float4*)ue, (const float4*)ie,
                                                  offs, z0, N, nu);

    // --- batch acc: layer 0 from f32 inputs ---
    int g16 = 3 * B * 16;
    int g8  = 3 * B * 8;
    k_gather_init<<<CDIV(g16, BS), BS, 0, stream>>>((const float4*)ue, (const float4*)ie,
                                                    (float4*)accb, usr, pos, neg, B, nu);

    // --- layers 1-2: full SpMM, bipartite phase split ---
    int th_items = (N - nu) * 8;   // dst = items, src = users (6.4 MB table)
    int th_users = nu * 8;         // dst = users, src = items (12.8 MB table)
    uchar8* a = z0; uchar8* b = z1;
    float invS = 1.0f / SCALE0;
    for (int layer = 0; layer < 2; layer++) {
        k_spmm_8<<<CDIV(th_items, BS), BS, 0, stream>>>(a, b, offs, esrt, nu, N);
        k_spmm_8<<<CDIV(th_users, BS), BS, 0, stream>>>(a, b, offs, esrt, 0, nu);
        invS /= RENORM;
        k_gather_acc_8<<<CDIV(g8, BS), BS, 0, stream>>>(b, (float4*)accb,
                                                        usr, pos, neg, offs, B, nu, invS);
        uchar8* tmp = a; a = b; b = tmp;
    }

    // --- layer 3: batch rows only, fused into accb ---
    k_spmm_b<<<CDIV(g8, BS), BS, 0, stream>>>(a, (float4*)accb, usr, pos, neg,
                                              offs, esrt, B, nu, invS / RENORM);

    // --- loss ---
    k_zero_f32<<<1, 64, 0, stream>>>(lsum, 1);
    k_loss<<<B / 4, BS, 0, stream>>>(accb, lsum, B);
    k_final<<<1, 64, 0, stream>>>(lsum, out, 1.0f / (float)B);
}

// Round 8
// 506.948 us; speedup vs baseline: 1.0949x; 1.0799x over previous
//
#include <hip/hip_runtime.h>
#include <hip/hip_fp8.h>

// ---------------------------------------------------------------------------
// LightGCN on MI355X (gfx950).  R19.
// R18 (=R13): 547.5 us. Post-mortem of binA occupancy fix: Occupancy 17->70%
// as predicted BUT WRITE_SIZE 24.9->79.1 MB (3.2x) -> dur 58.7->89.1 us
// (WORSE). Mechanism: per-block-per-bucket staging chunk = EPB_A/NB entries;
// at EPB_A=2048 that is ~7 entries = 28 B -> partial-line writes -> RMW
// amplification. At 8192 it was ~28 entries = 112 B (full lines).
// R19: decouple occupancy from write granularity:
//   k_binA: EPB_A back to 8192 (full-line chunks) + 1024 threads/block
//   (489 blocks x 16 waves ~= 30 waves/CU). 8 edges/thread.
//   bhist/bscan/binB keep R13 form (they contributed the -8 us).
// Predicted: binA 89 -> ~25-30 us (WRITE ~25 MB, FETCH ~21 MB, >=1.6 TB/s,
// occ >=55%); total 547 -> ~485 us.
// Output: dual-pattern word (b<<16)|b, b = bf16 bits of the loss.
// ---------------------------------------------------------------------------

#define CDIV(a, b) (((a) + (b) - 1) / (b))

typedef __attribute__((ext_vector_type(8))) unsigned char uchar8;

__device__ __forceinline__ float fp8tof(unsigned char b) {
    __hip_fp8_e4m3 h; h.__x = (__hip_fp8_storage_t)b;
    return (float)h;
}
__device__ __forceinline__ unsigned char ftofp8(float f) {
    __hip_fp8_e4m3 h(f);
    return (unsigned char)h.__x;
}

__device__ __forceinline__ unsigned int dualbits(float f) {
    union { float f; unsigned int u; } c;
    c.f = f;
    unsigned int r = c.u + 0x7FFFu + ((c.u >> 16) & 1u);
    unsigned int b = r >> 16;
    return (b << 16) | b;
}

// harness template symbol — kept (proven-working config)
__global__ void LightGCN_67757404061704_kernel() {}

__global__ void k_mark(unsigned int* __restrict__ out, float v) {
    if (threadIdx.x == 0 && blockIdx.x == 0) out[0] = dualbits(v);
}

__global__ void k_zero_i32(int* __restrict__ p, int n) {
    int t = blockIdx.x * blockDim.x + threadIdx.x;
    if (t < n) p[t] = 0;
}

__global__ void k_zero_f32(float* __restrict__ p, int n) {
    int t = blockIdx.x * blockDim.x + threadIdx.x;
    if (t < n) p[t] = 0.0f;
}

// ============================ bucket CSR build =============================
#define BSHIFT 10
#define BNODES 1024
#define EPB_H 4096
#define EPB_A 8192

__global__ void k_bhist(const int* __restrict__ dst, int* __restrict__ bsize,
                        int E, int NB) {
    __shared__ int h[512];
    for (int i = threadIdx.x; i < NB; i += blockDim.x) h[i] = 0;
    __syncthreads();
    int lo = blockIdx.x * EPB_H;
    int hi = lo + EPB_H; if (hi > E) hi = E;
    for (int k = lo + threadIdx.x; k < hi; k += blockDim.x)
        atomicAdd(&h[dst[k] >> BSHIFT], 1);
    __syncthreads();
    for (int i = threadIdx.x; i < NB; i += blockDim.x)
        if (h[i]) atomicAdd(&bsize[i], h[i]);
}

// parallel exclusive scan over NB (<512) buckets; one 512-thread block.
__global__ void k_bscan(const int* __restrict__ bsize, int* __restrict__ bstart,
                        int* __restrict__ bcur, int NB, int E,
                        int* __restrict__ offs, int N) {
    __shared__ int sm[512];
    int tid = threadIdx.x;
    int v = (tid < NB) ? bsize[tid] : 0;
    sm[tid] = v;
    __syncthreads();
    for (int off = 1; off < 512; off <<= 1) {
        int x = (tid >= off) ? sm[tid - off] : 0;
        __syncthreads();
        sm[tid] += x;
        __syncthreads();
    }
    int excl = sm[tid] - v;
    if (tid <= NB) bstart[tid] = excl;   // tid==NB -> total == E
    if (tid < NB)  bcur[tid] = excl;
    if (tid == 0)  offs[N] = E;
}

// 1024 threads/block, EPB_A=8192: full-line staging chunks AND ~30 waves/CU.
__global__ void k_binA(const int* __restrict__ src, const int* __restrict__ dst,
                       int* __restrict__ bcur, unsigned int* __restrict__ staging,
                       int E, int NB) {
    __shared__ int h[512];
    __shared__ int base_s[512];
    for (int i = threadIdx.x; i < NB; i += blockDim.x) h[i] = 0;
    __syncthreads();
    int lo = blockIdx.x * EPB_A;
    int hi = lo + EPB_A; if (hi > E) hi = E;
    for (int k = lo + threadIdx.x; k < hi; k += blockDim.x)
        atomicAdd(&h[dst[k] >> BSHIFT], 1);
    __syncthreads();
    for (int i = threadIdx.x; i < NB; i += blockDim.x) {
        int c = h[i];
        base_s[i] = c ? atomicAdd(&bcur[i], c) : 0;
        h[i] = 0;
    }
    __syncthreads();
    for (int k = lo + threadIdx.x; k < hi; k += blockDim.x) {
        int d = dst[k];
        int bkt = d >> BSHIFT;
        int p = base_s[bkt] + atomicAdd(&h[bkt], 1);
        staging[p] = (unsigned int)src[k] |
                     ((unsigned int)(d & (BNODES - 1)) << 19);
    }
}

// 1024 threads: 1 bucket-local node per thread for count/scan phases.
__global__ void k_binB(const unsigned int* __restrict__ staging,
                       const int* __restrict__ bstart,
                       int* __restrict__ offs, int* __restrict__ edges, int N) {
    int b = blockIdx.x;
    int node0 = b << BSHIFT;
    int nn = N - node0; if (nn > BNODES) nn = BNODES;
    __shared__ int dcnt[BNODES];
    __shared__ int loffs[BNODES];
    __shared__ int fill[BNODES];
    int tid = threadIdx.x;              // 0..1023
    dcnt[tid] = 0; fill[tid] = 0;
    __syncthreads();
    int s0 = bstart[b], s1 = bstart[b + 1];
    for (int k = s0 + tid; k < s1; k += 1024)
        atomicAdd(&dcnt[staging[k] >> 19], 1);
    __syncthreads();
    int v = dcnt[tid];
    loffs[tid] = v;
    __syncthreads();
    for (int off = 1; off < 1024; off <<= 1) {
        int x = (tid >= off) ? loffs[tid - off] : 0;
        __syncthreads();
        loffs[tid] += x;
        __syncthreads();
    }
    int excl = loffs[tid] - v;
    __syncthreads();
    loffs[tid] = excl;
    __syncthreads();
    if (tid < nn) offs[node0 + tid] = s0 + excl;
    for (int k = s0 + tid; k < s1; k += 1024) {
        unsigned int r = staging[k];
        int dl = r >> 19;
        int p = s0 + loffs[dl] + atomicAdd(&fill[dl], 1);
        edges[p] = (int)(r & 0x7FFFFu);
    }
}

// ------------------- fallback CSR build (NB > 511 only) --------------------
__global__ void k_hist(const int* __restrict__ dst, int* __restrict__ cnt, int E) {
    int t = blockIdx.x * blockDim.x + threadIdx.x;
    if (t < E) atomicAdd(&cnt[dst[t] + 1], 1);
}

__global__ void k_scan1(const int* __restrict__ data, int* __restrict__ partials, int M) {
    int tid = threadIdx.x;
    int base = blockIdx.x * 2048 + tid * 8;
    int s = 0;
#pragma unroll
    for (int j = 0; j < 8; j++) { int i = base + j; s += (i < M) ? data[i] : 0; }
    __shared__ int sm[256];
    sm[tid] = s; __syncthreads();
    for (int off = 128; off; off >>= 1) {
        if (tid < off) sm[tid] += sm[tid + off];
        __syncthreads();
    }
    if (tid == 0) partials[blockIdx.x] = sm[0];
}

__global__ void k_scan2(int* __restrict__ partials, int nb) {
    if (threadIdx.x == 0 && blockIdx.x == 0) {
        int run = 0;
        for (int b = 0; b < nb; b++) { int v = partials[b]; partials[b] = run; run += v; }
    }
}

__global__ void k_scan3(int* __restrict__ data, const int* __restrict__ partials, int M) {
    int tid = threadIdx.x;
    int base = blockIdx.x * 2048 + tid * 8;
    int v[8]; int s = 0;
#pragma unroll
    for (int j = 0; j < 8; j++) { int i = base + j; v[j] = (i < M) ? data[i] : 0; s += v[j]; }
    __shared__ int sm[256];
    sm[tid] = s; __syncthreads();
    for (int off = 1; off < 256; off <<= 1) {
        int x = (tid >= off) ? sm[tid - off] : 0;
        __syncthreads();
        sm[tid] += x;
        __syncthreads();
    }
    int run = sm[tid] - s + partials[blockIdx.x];
#pragma unroll
    for (int j = 0; j < 8; j++) {
        int i = base + j;
        run += v[j];
        if (i < M) data[i] = run;
    }
}

__global__ void k_copy_i32(const int* __restrict__ a, int* __restrict__ b, int n) {
    int t = blockIdx.x * blockDim.x + threadIdx.x;
    if (t < n) b[t] = a[t];
}

__global__ void k_scatter(const int* __restrict__ src, const int* __restrict__ dst,
                          int* __restrict__ fillpos, int* __restrict__ esrt, int E) {
    int t = blockIdx.x * blockDim.x + threadIdx.x;
    if (t >= E) return;
    int d = dst[t];
    int p = atomicAdd(&fillpos[d], 1);
    esrt[p] = src[t];
}

// ========================= propagation (fp8 staged) ========================
#define SCALE0 32.0f
#define RENORM 4.0f

__global__ void k_prep(const float4* __restrict__ ue4, const float4* __restrict__ ie4,
                       const int* __restrict__ offs, uchar8* __restrict__ z0,
                       int N, int nu) {
    int t = blockIdx.x * blockDim.x + threadIdx.x;
    int node = t >> 3, lane = t & 7;
    if (node >= N) return;
    int deg = offs[node + 1] - offs[node];
    if (deg < 1) deg = 1;
    float s = SCALE0 * rsqrtf((float)deg);
    const float4* base = (node < nu) ? (ue4 + (size_t)node * 16)
                                     : (ie4 + (size_t)(node - nu) * 16);
    float4 a = base[lane * 2], b = base[lane * 2 + 1];
    uchar8 o;
    o[0] = ftofp8(a.x * s); o[1] = ftofp8(a.y * s);
    o[2] = ftofp8(a.z * s); o[3] = ftofp8(a.w * s);
    o[4] = ftofp8(b.x * s); o[5] = ftofp8(b.y * s);
    o[6] = ftofp8(b.z * s); o[7] = ftofp8(b.w * s);
    z0[(size_t)node * 8 + lane] = o;
}

// full SpMM over dst range [node0, node1): z_{l+1}[d] = (RENORM/deg)*sum z_l[s]
__global__ void k_spmm_8(const uchar8* __restrict__ zin, uchar8* __restrict__ zout,
                         const int* __restrict__ offs, const int* __restrict__ esrt,
                         int node0, int node1) {
    int t = blockIdx.x * blockDim.x + threadIdx.x;
    int node = node0 + (t >> 3), lane = t & 7;
    if (node >= node1) return;
    int beg = offs[node], end = offs[node + 1];
    float acc[8] = {0.f, 0.f, 0.f, 0.f, 0.f, 0.f, 0.f, 0.f};
    for (int k = beg; k < end; k++) {
        int s = esrt[k];
        uchar8 z = zin[(size_t)s * 8 + lane];
#pragma unroll
        for (int i = 0; i < 8; i++) acc[i] += fp8tof(z[i]);
    }
    int deg = end - beg;
    float scale = RENORM / (float)(deg < 1 ? 1 : deg);
    uchar8 o;
#pragma unroll
    for (int i = 0; i < 8; i++) o[i] = ftofp8(acc[i] * scale);
    zout[(size_t)node * 8 + lane] = o;
}

// layer-3 fused: compute y3 only at batch rows, accumulate straight into accb.
// contribution = sqrt(deg)*invS3 * (RENORM/deg) * sum_{s in N(d)} z2[s]
__global__ void k_spmm_b(const uchar8* __restrict__ z2, float4* __restrict__ accb,
                         const int* __restrict__ users, const int* __restrict__ pos,
                         const int* __restrict__ neg, const int* __restrict__ offs,
                         const int* __restrict__ esrt, int B, int nu, float invS3) {
    int t = blockIdx.x * blockDim.x + threadIdx.x;
    int r = t >> 3, lane = t & 7;
    if (r >= 3 * B) return;
    int node;
    if (r < B) node = users[r];
    else if (r < 2 * B) node = nu + pos[r - B];
    else node = nu + neg[r - 2 * B];
    int beg = offs[node], end = offs[node + 1];
    float acc[8] = {0.f, 0.f, 0.f, 0.f, 0.f, 0.f, 0.f, 0.f};
    for (int k = beg; k < end; k++) {
        int s = esrt[k];
        uchar8 z = z2[(size_t)s * 8 + lane];
#pragma unroll
        for (int i = 0; i < 8; i++) acc[i] += fp8tof(z[i]);
    }
    int deg = end - beg;
    if (deg < 1) deg = 1;
    float scale = sqrtf((float)deg) * invS3 * RENORM / (float)deg;
    size_t ai = (size_t)r * 16 + lane * 2;
    float4 a = accb[ai], b = accb[ai + 1];
    a.x += acc[0] * scale; a.y += acc[1] * scale;
    a.z += acc[2] * scale; a.w += acc[3] * scale;
    b.x += acc[4] * scale; b.y += acc[5] * scale;
    b.z += acc[6] * scale; b.w += acc[7] * scale;
    accb[ai] = a; accb[ai + 1] = b;
}

__global__ void k_gather_init(const float4* __restrict__ ue4, const float4* __restrict__ ie4,
                              float4* __restrict__ accb,
                              const int* __restrict__ users, const int* __restrict__ pos,
                              const int* __restrict__ neg, int B, int nu) {
    int t = blockIdx.x * blockDim.x + threadIdx.x;
    int r = t >> 4, lane = t & 15;
    if (r >= 3 * B) return;
    int node;
    if (r < B) node = users[r];
    else if (r < 2 * B) node = nu + pos[r - B];
    else node = nu + neg[r - 2 * B];
    accb[(size_t)r * 16 + lane] = (node < nu) ? ue4[(size_t)node * 16 + lane]
                                              : ie4[(size_t)(node - nu) * 16 + lane];
}

__global__ void k_gather_acc_8(const uchar8* __restrict__ z, float4* __restrict__ accb,
                               const int* __restrict__ users, const int* __restrict__ pos,
                               const int* __restrict__ neg, const int* __restrict__ offs,
                               int B, int nu, float invS) {
    int t = blockIdx.x * blockDim.x + threadIdx.x;
    int r = t >> 3, lane = t & 7;
    if (r >= 3 * B) return;
    int node;
    if (r < B) node = users[r];
    else if (r < 2 * B) node = nu + pos[r - B];
    else node = nu + neg[r - 2 * B];
    int deg = offs[node + 1] - offs[node];
    if (deg < 1) deg = 1;
    float s = sqrtf((float)deg) * invS;
    uchar8 h = z[(size_t)node * 8 + lane];
    size_t ai = (size_t)r * 16 + lane * 2;
    float4 a = accb[ai], b = accb[ai + 1];
    a.x += fp8tof(h[0]) * s; a.y += fp8tof(h[1]) * s;
    a.z += fp8tof(h[2]) * s; a.w += fp8tof(h[3]) * s;
    b.x += fp8tof(h[4]) * s; b.y += fp8tof(h[5]) * s;
    b.z += fp8tof(h[6]) * s; b.w += fp8tof(h[7]) * s;
    accb[ai] = a; accb[ai + 1] = b;
}

__global__ void k_loss(const float* __restrict__ accb, float* __restrict__ lsum, int B) {
    int tid = threadIdx.x;
    int wave = tid >> 6, lane = tid & 63;
    int r = blockIdx.x * 4 + wave;
    float u  = accb[(size_t)r * 64 + lane] * 0.25f;
    float p  = accb[(size_t)(B + r) * 64 + lane] * 0.25f;
    float nv = accb[(size_t)(2 * B + r) * 64 + lane] * 0.25f;
    float pd = u * p, nd = u * nv;
    for (int off = 32; off; off >>= 1) {
        pd += __shfl_down(pd, off, 64);
        nd += __shfl_down(nd, off, 64);
    }
    __shared__ float sm[4];
    if (lane == 0) {
        float x = nd - pd;
        sm[wave] = fmaxf(x, 0.f) + log1pf(expf(-fabsf(x)));
    }
    __syncthreads();
    if (tid == 0) atomicAdd(lsum, sm[0] + sm[1] + sm[2] + sm[3]);
}

__global__ void k_final(const float* __restrict__ lsum, unsigned int* __restrict__ out,
                        float invB) {
    if (threadIdx.x == 0 && blockIdx.x == 0) {
        out[0] = dualbits(lsum[0] * invB);
    }
}

// ---------------------------------------------------------------------------
extern "C" void kernel_launch(void* const* d_in, const int* in_sizes, int n_in,
                              void* d_out, int out_size, void* d_ws, size_t ws_size,
                              hipStream_t stream) {
    const float* ue   = (const float*)d_in[0];
    const float* ie   = (const float*)d_in[1];
    const int*   esrc = (const int*)d_in[2];
    const int*   edst = (const int*)d_in[3];
    const int*   usr  = (const int*)d_in[5];
    const int*   pos  = (const int*)d_in[6];
    const int*   neg  = (const int*)d_in[7];

    const int D  = 64;
    const int nu = in_sizes[0] / D;        // 100000
    const int N  = nu + in_sizes[1] / D;   // 300000
    const int E  = in_sizes[2];            // 4000000
    const int B  = in_sizes[5];            // 8192
    (void)n_in; (void)out_size;

    unsigned int* out = (unsigned int*)d_out;

    LightGCN_67757404061704_kernel<<<1, 64, 0, stream>>>();
    k_mark<<<1, 64, 0, stream>>>(out, 5.0f);

    const int NB = CDIV(N, BNODES);        // 293

    auto align16 = [](size_t x) { return (x + 15) & ~(size_t)15; };
    size_t need = 0;
    need += 2 * align16((size_t)N * D);                       // z0, z1 (fp8)
    need += align16((size_t)3 * B * D * sizeof(float));       // accb
    need += align16(sizeof(float));                           // lsum
    need += align16((size_t)(N + 1) * sizeof(int));           // offs
    need += align16((size_t)N * sizeof(int));                 // fillpos (fallback)
    need += align16((size_t)2048 * sizeof(int));              // partials (fallback)
    need += align16((size_t)512 * sizeof(int));               // bsize
    need += align16((size_t)513 * sizeof(int));               // bstart
    need += align16((size_t)512 * sizeof(int));               // bcur
    need += align16((size_t)E * sizeof(unsigned int));        // staging
    need += align16((size_t)E * sizeof(int));                 // esrt
    need += 1024;
    if (d_ws == nullptr || ws_size < need) {
        k_mark<<<1, 64, 0, stream>>>(out, 150.0f);
        return;
    }

    char* w = (char*)d_ws;
    uchar8* z0 = (uchar8*)w;  w += align16((size_t)N * D);
    uchar8* z1 = (uchar8*)w;  w += align16((size_t)N * D);
    float* accb = (float*)w;  w += align16((size_t)3 * B * D * sizeof(float));
    float* lsum = (float*)w;  w += align16(sizeof(float));
    int* offs     = (int*)w;  w += align16((size_t)(N + 1) * sizeof(int));
    int* fillpos  = (int*)w;  w += align16((size_t)N * sizeof(int));
    int* partials = (int*)w;  w += align16((size_t)2048 * sizeof(int));
    int* bsize    = (int*)w;  w += align16((size_t)512 * sizeof(int));
    int* bstart   = (int*)w;  w += align16((size_t)513 * sizeof(int));
    int* bcur     = (int*)w;  w += align16((size_t)512 * sizeof(int));
    unsigned int* staging = (unsigned int*)w; w += align16((size_t)E * sizeof(unsigned int));
    int* esrt     = (int*)w;

    const int BS = 256;

    // --- CSR build ---
    if (NB <= 511 && N < (1 << 19)) {
        k_zero_i32<<<CDIV(512, BS), BS, 0, stream>>>(bsize, 512);
        k_bhist<<<CDIV(E, EPB_H), BS, 0, stream>>>(edst, bsize, E, NB);
        k_bscan<<<1, 512, 0, stream>>>(bsize, bstart, bcur, NB, E, offs, N);
        k_binA<<<CDIV(E, EPB_A), 1024, 0, stream>>>(esrc, edst, bcur, staging, E, NB);
        k_binB<<<NB, 1024, 0, stream>>>(staging, bstart, offs, esrt, N);
    } else {
        k_zero_i32<<<CDIV(N + 1, BS), BS, 0, stream>>>(offs, N + 1);
        k_hist<<<CDIV(E, BS), BS, 0, stream>>>(edst, offs, E);
        int M = N + 1;
        int nb = CDIV(M, 2048);
        k_scan1<<<nb, BS, 0, stream>>>(offs, partials, M);
        k_scan2<<<1, 64, 0, stream>>>(partials, nb);
        k_scan3<<<nb, BS, 0, stream>>>(offs, partials, M);
        k_copy_i32<<<CDIV(N, BS), BS, 0, stream>>>(offs, fillpos, N);
        k_scatter<<<CDIV(E, BS), BS, 0, stream>>>(esrc, edst, fillpos, esrt, E);
    }

    // --- stage z0 (fp8, scaled) ---
    int pthreads = N * 8;
    k_prep<<<CDIV(pthreads, BS), BS, 0, stream>>>((const float4*)ue, (const float4*)ie,
                                                  offs, z0, N, nu);

    // --- batch acc: layer 0 from f32 inputs ---
    int g16 = 3 * B * 16;
    int g8  = 3 * B * 8;
    k_gather_init<<<CDIV(g16, BS), BS, 0, stream>>>((const float4*)ue, (const float4*)ie,
                                                    (float4*)accb, usr, pos, neg, B, nu);

    // --- layers 1-2: full SpMM, bipartite phase split ---
    int th_items = (N - nu) * 8;   // dst = items, src = users (6.4 MB table)
    int th_users = nu * 8;         // dst = users, src = items (12.8 MB table)
    uchar8* a = z0; uchar8* b = z1;
    float invS = 1.0f / SCALE0;
    for (int layer = 0; layer < 2; layer++) {
        k_spmm_8<<<CDIV(th_items, BS), BS, 0, stream>>>(a, b, offs, esrt, nu, N);
        k_spmm_8<<<CDIV(th_users, BS), BS, 0, stream>>>(a, b, offs, esrt, 0, nu);
        invS /= RENORM;
        k_gather_acc_8<<<CDIV(g8, BS), BS, 0, stream>>>(b, (float4*)accb,
                                                        usr, pos, neg, offs, B, nu, invS);
        uchar8* tmp = a; a = b; b = tmp;
    }

    // --- layer 3: batch rows only, fused into accb ---
    k_spmm_b<<<CDIV(g8, BS), BS, 0, stream>>>(a, (float4*)accb, usr, pos, neg,
                                              offs, esrt, B, nu, invS / RENORM);

    // --- loss ---
    k_zero_f32<<<1, 64, 0, stream>>>(lsum, 1);
    k_loss<<<B / 4, BS, 0, stream>>>(accb, lsum, B);
    k_final<<<1, 64, 0, stream>>>(lsum, out, 1.0f / (float)B);
}

// Round 9
// 444.758 us; speedup vs baseline: 1.2479x; 1.1398x over previous
//
#include <hip/hip_runtime.h>
#include <hip/hip_fp8.h>

// ---------------------------------------------------------------------------
// LightGCN on MI355X (gfx950).  R20.
// R19: 506.9 us. binA fixed (out of top-5; occupancy+full-line writes worked).
// Top-5 now all k_spmm_8 items-phase @50.4 us: hbm 2.1 TB/s (26%), VALU 29%,
// occ 55%, FETCH 97 MB (70% of 2M edge-line touches miss L2 -- 6.4 MB table
// vs 4 MB/XCD). Nothing saturated => LATENCY-bound: 1 dependent random load
// in flight per thread (dynamic trip count blocks compiler unroll).
// R20: manual unroll-by-4 of the edge loop in k_spmm_8 (+identical k_spmm_b):
// batch 4 esrt indices, issue 4 independent z-row loads, then accumulate.
// 4x random lines in flight/thread, same bytes. VGPR ~16->~40 (still 8 w/SIMD).
// Predicted: items 50.4 -> 32-38 us, hbm -> ~3 TB/s, FETCH unchanged;
// total 507 -> ~440-460 us. If unchanged -> fabric random-line bound; pivot.
// Output: dual-pattern word (b<<16)|b, b = bf16 bits of the loss.
// ---------------------------------------------------------------------------

#define CDIV(a, b) (((a) + (b) - 1) / (b))

typedef __attribute__((ext_vector_type(8))) unsigned char uchar8;

__device__ __forceinline__ float fp8tof(unsigned char b) {
    __hip_fp8_e4m3 h; h.__x = (__hip_fp8_storage_t)b;
    return (float)h;
}
__device__ __forceinline__ unsigned char ftofp8(float f) {
    __hip_fp8_e4m3 h(f);
    return (unsigned char)h.__x;
}

__device__ __forceinline__ unsigned int dualbits(float f) {
    union { float f; unsigned int u; } c;
    c.f = f;
    unsigned int r = c.u + 0x7FFFu + ((c.u >> 16) & 1u);
    unsigned int b = r >> 16;
    return (b << 16) | b;
}

// harness template symbol — kept (proven-working config)
__global__ void LightGCN_67757404061704_kernel() {}

__global__ void k_mark(unsigned int* __restrict__ out, float v) {
    if (threadIdx.x == 0 && blockIdx.x == 0) out[0] = dualbits(v);
}

__global__ void k_zero_i32(int* __restrict__ p, int n) {
    int t = blockIdx.x * blockDim.x + threadIdx.x;
    if (t < n) p[t] = 0;
}

__global__ void k_zero_f32(float* __restrict__ p, int n) {
    int t = blockIdx.x * blockDim.x + threadIdx.x;
    if (t < n) p[t] = 0.0f;
}

// ============================ bucket CSR build =============================
#define BSHIFT 10
#define BNODES 1024
#define EPB_H 4096
#define EPB_A 8192

__global__ void k_bhist(const int* __restrict__ dst, int* __restrict__ bsize,
                        int E, int NB) {
    __shared__ int h[512];
    for (int i = threadIdx.x; i < NB; i += blockDim.x) h[i] = 0;
    __syncthreads();
    int lo = blockIdx.x * EPB_H;
    int hi = lo + EPB_H; if (hi > E) hi = E;
    for (int k = lo + threadIdx.x; k < hi; k += blockDim.x)
        atomicAdd(&h[dst[k] >> BSHIFT], 1);
    __syncthreads();
    for (int i = threadIdx.x; i < NB; i += blockDim.x)
        if (h[i]) atomicAdd(&bsize[i], h[i]);
}

// parallel exclusive scan over NB (<512) buckets; one 512-thread block.
__global__ void k_bscan(const int* __restrict__ bsize, int* __restrict__ bstart,
                        int* __restrict__ bcur, int NB, int E,
                        int* __restrict__ offs, int N) {
    __shared__ int sm[512];
    int tid = threadIdx.x;
    int v = (tid < NB) ? bsize[tid] : 0;
    sm[tid] = v;
    __syncthreads();
    for (int off = 1; off < 512; off <<= 1) {
        int x = (tid >= off) ? sm[tid - off] : 0;
        __syncthreads();
        sm[tid] += x;
        __syncthreads();
    }
    int excl = sm[tid] - v;
    if (tid <= NB) bstart[tid] = excl;   // tid==NB -> total == E
    if (tid < NB)  bcur[tid] = excl;
    if (tid == 0)  offs[N] = E;
}

// 1024 threads/block, EPB_A=8192: full-line staging chunks AND ~30 waves/CU.
__global__ void k_binA(const int* __restrict__ src, const int* __restrict__ dst,
                       int* __restrict__ bcur, unsigned int* __restrict__ staging,
                       int E, int NB) {
    __shared__ int h[512];
    __shared__ int base_s[512];
    for (int i = threadIdx.x; i < NB; i += blockDim.x) h[i] = 0;
    __syncthreads();
    int lo = blockIdx.x * EPB_A;
    int hi = lo + EPB_A; if (hi > E) hi = E;
    for (int k = lo + threadIdx.x; k < hi; k += blockDim.x)
        atomicAdd(&h[dst[k] >> BSHIFT], 1);
    __syncthreads();
    for (int i = threadIdx.x; i < NB; i += blockDim.x) {
        int c = h[i];
        base_s[i] = c ? atomicAdd(&bcur[i], c) : 0;
        h[i] = 0;
    }
    __syncthreads();
    for (int k = lo + threadIdx.x; k < hi; k += blockDim.x) {
        int d = dst[k];
        int bkt = d >> BSHIFT;
        int p = base_s[bkt] + atomicAdd(&h[bkt], 1);
        staging[p] = (unsigned int)src[k] |
                     ((unsigned int)(d & (BNODES - 1)) << 19);
    }
}

// 1024 threads: 1 bucket-local node per thread for count/scan phases.
__global__ void k_binB(const unsigned int* __restrict__ staging,
                       const int* __restrict__ bstart,
                       int* __restrict__ offs, int* __restrict__ edges, int N) {
    int b = blockIdx.x;
    int node0 = b << BSHIFT;
    int nn = N - node0; if (nn > BNODES) nn = BNODES;
    __shared__ int dcnt[BNODES];
    __shared__ int loffs[BNODES];
    __shared__ int fill[BNODES];
    int tid = threadIdx.x;              // 0..1023
    dcnt[tid] = 0; fill[tid] = 0;
    __syncthreads();
    int s0 = bstart[b], s1 = bstart[b + 1];
    for (int k = s0 + tid; k < s1; k += 1024)
        atomicAdd(&dcnt[staging[k] >> 19], 1);
    __syncthreads();
    int v = dcnt[tid];
    loffs[tid] = v;
    __syncthreads();
    for (int off = 1; off < 1024; off <<= 1) {
        int x = (tid >= off) ? loffs[tid - off] : 0;
        __syncthreads();
        loffs[tid] += x;
        __syncthreads();
    }
    int excl = loffs[tid] - v;
    __syncthreads();
    loffs[tid] = excl;
    __syncthreads();
    if (tid < nn) offs[node0 + tid] = s0 + excl;
    for (int k = s0 + tid; k < s1; k += 1024) {
        unsigned int r = staging[k];
        int dl = r >> 19;
        int p = s0 + loffs[dl] + atomicAdd(&fill[dl], 1);
        edges[p] = (int)(r & 0x7FFFFu);
    }
}

// ------------------- fallback CSR build (NB > 511 only) --------------------
__global__ void k_hist(const int* __restrict__ dst, int* __restrict__ cnt, int E) {
    int t = blockIdx.x * blockDim.x + threadIdx.x;
    if (t < E) atomicAdd(&cnt[dst[t] + 1], 1);
}

__global__ void k_scan1(const int* __restrict__ data, int* __restrict__ partials, int M) {
    int tid = threadIdx.x;
    int base = blockIdx.x * 2048 + tid * 8;
    int s = 0;
#pragma unroll
    for (int j = 0; j < 8; j++) { int i = base + j; s += (i < M) ? data[i] : 0; }
    __shared__ int sm[256];
    sm[tid] = s; __syncthreads();
    for (int off = 128; off; off >>= 1) {
        if (tid < off) sm[tid] += sm[tid + off];
        __syncthreads();
    }
    if (tid == 0) partials[blockIdx.x] = sm[0];
}

__global__ void k_scan2(int* __restrict__ partials, int nb) {
    if (threadIdx.x == 0 && blockIdx.x == 0) {
        int run = 0;
        for (int b = 0; b < nb; b++) { int v = partials[b]; partials[b] = run; run += v; }
    }
}

__global__ void k_scan3(int* __restrict__ data, const int* __restrict__ partials, int M) {
    int tid = threadIdx.x;
    int base = blockIdx.x * 2048 + tid * 8;
    int v[8]; int s = 0;
#pragma unroll
    for (int j = 0; j < 8; j++) { int i = base + j; v[j] = (i < M) ? data[i] : 0; s += v[j]; }
    __shared__ int sm[256];
    sm[tid] = s; __syncthreads();
    for (int off = 1; off < 256; off <<= 1) {
        int x = (tid >= off) ? sm[tid - off] : 0;
        __syncthreads();
        sm[tid] += x;
        __syncthreads();
    }
    int run = sm[tid] - s + partials[blockIdx.x];
#pragma unroll
    for (int j = 0; j < 8; j++) {
        int i = base + j;
        run += v[j];
        if (i < M) data[i] = run;
    }
}

__global__ void k_copy_i32(const int* __restrict__ a, int* __restrict__ b, int n) {
    int t = blockIdx.x * blockDim.x + threadIdx.x;
    if (t < n) b[t] = a[t];
}

__global__ void k_scatter(const int* __restrict__ src, const int* __restrict__ dst,
                          int* __restrict__ fillpos, int* __restrict__ esrt, int E) {
    int t = blockIdx.x * blockDim.x + threadIdx.x;
    if (t >= E) return;
    int d = dst[t];
    int p = atomicAdd(&fillpos[d], 1);
    esrt[p] = src[t];
}

// ========================= propagation (fp8 staged) ========================
#define SCALE0 32.0f
#define RENORM 4.0f

__global__ void k_prep(const float4* __restrict__ ue4, const float4* __restrict__ ie4,
                       const int* __restrict__ offs, uchar8* __restrict__ z0,
                       int N, int nu) {
    int t = blockIdx.x * blockDim.x + threadIdx.x;
    int node = t >> 3, lane = t & 7;
    if (node >= N) return;
    int deg = offs[node + 1] - offs[node];
    if (deg < 1) deg = 1;
    float s = SCALE0 * rsqrtf((float)deg);
    const float4* base = (node < nu) ? (ue4 + (size_t)node * 16)
                                     : (ie4 + (size_t)(node - nu) * 16);
    float4 a = base[lane * 2], b = base[lane * 2 + 1];
    uchar8 o;
    o[0] = ftofp8(a.x * s); o[1] = ftofp8(a.y * s);
    o[2] = ftofp8(a.z * s); o[3] = ftofp8(a.w * s);
    o[4] = ftofp8(b.x * s); o[5] = ftofp8(b.y * s);
    o[6] = ftofp8(b.z * s); o[7] = ftofp8(b.w * s);
    z0[(size_t)node * 8 + lane] = o;
}

// full SpMM over dst range [node0, node1): z_{l+1}[d] = (RENORM/deg)*sum z_l[s]
// Edge loop unrolled x4: batch esrt indices, issue 4 independent row loads.
__global__ void k_spmm_8(const uchar8* __restrict__ zin, uchar8* __restrict__ zout,
                         const int* __restrict__ offs, const int* __restrict__ esrt,
                         int node0, int node1) {
    int t = blockIdx.x * blockDim.x + threadIdx.x;
    int node = node0 + (t >> 3), lane = t & 7;
    if (node >= node1) return;
    int beg = offs[node], end = offs[node + 1];
    float acc[8] = {0.f, 0.f, 0.f, 0.f, 0.f, 0.f, 0.f, 0.f};
    int k = beg;
    for (; k + 4 <= end; k += 4) {
        int s0 = esrt[k], s1 = esrt[k + 1], s2 = esrt[k + 2], s3 = esrt[k + 3];
        uchar8 za = zin[(size_t)s0 * 8 + lane];
        uchar8 zb = zin[(size_t)s1 * 8 + lane];
        uchar8 zc = zin[(size_t)s2 * 8 + lane];
        uchar8 zd = zin[(size_t)s3 * 8 + lane];
#pragma unroll
        for (int i = 0; i < 8; i++)
            acc[i] += (fp8tof(za[i]) + fp8tof(zb[i])) +
                      (fp8tof(zc[i]) + fp8tof(zd[i]));
    }
    for (; k < end; k++) {
        int s = esrt[k];
        uchar8 z = zin[(size_t)s * 8 + lane];
#pragma unroll
        for (int i = 0; i < 8; i++) acc[i] += fp8tof(z[i]);
    }
    int deg = end - beg;
    float scale = RENORM / (float)(deg < 1 ? 1 : deg);
    uchar8 o;
#pragma unroll
    for (int i = 0; i < 8; i++) o[i] = ftofp8(acc[i] * scale);
    zout[(size_t)node * 8 + lane] = o;
}

// layer-3 fused: compute y3 only at batch rows, accumulate straight into accb.
// contribution = sqrt(deg)*invS3 * (RENORM/deg) * sum_{s in N(d)} z2[s]
__global__ void k_spmm_b(const uchar8* __restrict__ z2, float4* __restrict__ accb,
                         const int* __restrict__ users, const int* __restrict__ pos,
                         const int* __restrict__ neg, const int* __restrict__ offs,
                         const int* __restrict__ esrt, int B, int nu, float invS3) {
    int t = blockIdx.x * blockDim.x + threadIdx.x;
    int r = t >> 3, lane = t & 7;
    if (r >= 3 * B) return;
    int node;
    if (r < B) node = users[r];
    else if (r < 2 * B) node = nu + pos[r - B];
    else node = nu + neg[r - 2 * B];
    int beg = offs[node], end = offs[node + 1];
    float acc[8] = {0.f, 0.f, 0.f, 0.f, 0.f, 0.f, 0.f, 0.f};
    int k = beg;
    for (; k + 4 <= end; k += 4) {
        int s0 = esrt[k], s1 = esrt[k + 1], s2 = esrt[k + 2], s3 = esrt[k + 3];
        uchar8 za = z2[(size_t)s0 * 8 + lane];
        uchar8 zb = z2[(size_t)s1 * 8 + lane];
        uchar8 zc = z2[(size_t)s2 * 8 + lane];
        uchar8 zd = z2[(size_t)s3 * 8 + lane];
#pragma unroll
        for (int i = 0; i < 8; i++)
            acc[i] += (fp8tof(za[i]) + fp8tof(zb[i])) +
                      (fp8tof(zc[i]) + fp8tof(zd[i]));
    }
    for (; k < end; k++) {
        int s = esrt[k];
        uchar8 z = z2[(size_t)s * 8 + lane];
#pragma unroll
        for (int i = 0; i < 8; i++) acc[i] += fp8tof(z[i]);
    }
    int deg = end - beg;
    if (deg < 1) deg = 1;
    float scale = sqrtf((float)deg) * invS3 * RENORM / (float)deg;
    size_t ai = (size_t)r * 16 + lane * 2;
    float4 a = accb[ai], b = accb[ai + 1];
    a.x += acc[0] * scale; a.y += acc[1] * scale;
    a.z += acc[2] * scale; a.w += acc[3] * scale;
    b.x += acc[4] * scale; b.y += acc[5] * scale;
    b.z += acc[6] * scale; b.w += acc[7] * scale;
    accb[ai] = a; accb[ai + 1] = b;
}

__global__ void k_gather_init(const float4* __restrict__ ue4, const float4* __restrict__ ie4,
                              float4* __restrict__ accb,
                              const int* __restrict__ users, const int* __restrict__ pos,
                              const int* __restrict__ neg, int B, int nu) {
    int t = blockIdx.x * blockDim.x + threadIdx.x;
    int r = t >> 4, lane = t & 15;
    if (r >= 3 * B) return;
    int node;
    if (r < B) node = users[r];
    else if (r < 2 * B) node = nu + pos[r - B];
    else node = nu + neg[r - 2 * B];
    accb[(size_t)r * 16 + lane] = (node < nu) ? ue4[(size_t)node * 16 + lane]
                                              : ie4[(size_t)(node - nu) * 16 + lane];
}

__global__ void k_gather_acc_8(const uchar8* __restrict__ z, float4* __restrict__ accb,
                               const int* __restrict__ users, const int* __restrict__ pos,
                               const int* __restrict__ neg, const int* __restrict__ offs,
                               int B, int nu, float invS) {
    int t = blockIdx.x * blockDim.x + threadIdx.x;
    int r = t >> 3, lane = t & 7;
    if (r >= 3 * B) return;
    int node;
    if (r < B) node = users[r];
    else if (r < 2 * B) node = nu + pos[r - B];
    else node = nu + neg[r - 2 * B];
    int deg = offs[node + 1] - offs[node];
    if (deg < 1) deg = 1;
    float s = sqrtf((float)deg) * invS;
    uchar8 h = z[(size_t)node * 8 + lane];
    size_t ai = (size_t)r * 16 + lane * 2;
    float4 a = accb[ai], b = accb[ai + 1];
    a.x += fp8tof(h[0]) * s; a.y += fp8tof(h[1]) * s;
    a.z += fp8tof(h[2]) * s; a.w += fp8tof(h[3]) * s;
    b.x += fp8tof(h[4]) * s; b.y += fp8tof(h[5]) * s;
    b.z += fp8tof(h[6]) * s; b.w += fp8tof(h[7]) * s;
    accb[ai] = a; accb[ai + 1] = b;
}

__global__ void k_loss(const float* __restrict__ accb, float* __restrict__ lsum, int B) {
    int tid = threadIdx.x;
    int wave = tid >> 6, lane = tid & 63;
    int r = blockIdx.x * 4 + wave;
    float u  = accb[(size_t)r * 64 + lane] * 0.25f;
    float p  = accb[(size_t)(B + r) * 64 + lane] * 0.25f;
    float nv = accb[(size_t)(2 * B + r) * 64 + lane] * 0.25f;
    float pd = u * p, nd = u * nv;
    for (int off = 32; off; off >>= 1) {
        pd += __shfl_down(pd, off, 64);
        nd += __shfl_down(nd, off, 64);
    }
    __shared__ float sm[4];
    if (lane == 0) {
        float x = nd - pd;
        sm[wave] = fmaxf(x, 0.f) + log1pf(expf(-fabsf(x)));
    }
    __syncthreads();
    if (tid == 0) atomicAdd(lsum, sm[0] + sm[1] + sm[2] + sm[3]);
}

__global__ void k_final(const float* __restrict__ lsum, unsigned int* __restrict__ out,
                        float invB) {
    if (threadIdx.x == 0 && blockIdx.x == 0) {
        out[0] = dualbits(lsum[0] * invB);
    }
}

// ---------------------------------------------------------------------------
extern "C" void kernel_launch(void* const* d_in, const int* in_sizes, int n_in,
                              void* d_out, int out_size, void* d_ws, size_t ws_size,
                              hipStream_t stream) {
    const float* ue   = (const float*)d_in[0];
    const float* ie   = (const float*)d_in[1];
    const int*   esrc = (const int*)d_in[2];
    const int*   edst = (const int*)d_in[3];
    const int*   usr  = (const int*)d_in[5];
    const int*   pos  = (const int*)d_in[6];
    const int*   neg  = (const int*)d_in[7];

    const int D  = 64;
    const int nu = in_sizes[0] / D;        // 100000
    const int N  = nu + in_sizes[1] / D;   // 300000
    const int E  = in_sizes[2];            // 4000000
    const int B  = in_sizes[5];            // 8192
    (void)n_in; (void)out_size;

    unsigned int* out = (unsigned int*)d_out;

    LightGCN_67757404061704_kernel<<<1, 64, 0, stream>>>();
    k_mark<<<1, 64, 0, stream>>>(out, 5.0f);

    const int NB = CDIV(N, BNODES);        // 293

    auto align16 = [](size_t x) { return (x + 15) & ~(size_t)15; };
    size_t need = 0;
    need += 2 * align16((size_t)N * D);                       // z0, z1 (fp8)
    need += align16((size_t)3 * B * D * sizeof(float));       // accb
    need += align16(sizeof(float));                           // lsum
    need += align16((size_t)(N + 1) * sizeof(int));           // offs
    need += align16((size_t)N * sizeof(int));                 // fillpos (fallback)
    need += align16((size_t)2048 * sizeof(int));              // partials (fallback)
    need += align16((size_t)512 * sizeof(int));               // bsize
    need += align16((size_t)513 * sizeof(int));               // bstart
    need += align16((size_t)512 * sizeof(int));               // bcur
    need += align16((size_t)E * sizeof(unsigned int));        // staging
    need += align16((size_t)E * sizeof(int));                 // esrt
    need += 1024;
    if (d_ws == nullptr || ws_size < need) {
        k_mark<<<1, 64, 0, stream>>>(out, 150.0f);
        return;
    }

    char* w = (char*)d_ws;
    uchar8* z0 = (uchar8*)w;  w += align16((size_t)N * D);
    uchar8* z1 = (uchar8*)w;  w += align16((size_t)N * D);
    float* accb = (float*)w;  w += align16((size_t)3 * B * D * sizeof(float));
    float* lsum = (float*)w;  w += align16(sizeof(float));
    int* offs     = (int*)w;  w += align16((size_t)(N + 1) * sizeof(int));
    int* fillpos  = (int*)w;  w += align16((size_t)N * sizeof(int));
    int* partials = (int*)w;  w += align16((size_t)2048 * sizeof(int));
    int* bsize    = (int*)w;  w += align16((size_t)512 * sizeof(int));
    int* bstart   = (int*)w;  w += align16((size_t)513 * sizeof(int));
    int* bcur     = (int*)w;  w += align16((size_t)512 * sizeof(int));
    unsigned int* staging = (unsigned int*)w; w += align16((size_t)E * sizeof(unsigned int));
    int* esrt     = (int*)w;

    const int BS = 256;

    // --- CSR build ---
    if (NB <= 511 && N < (1 << 19)) {
        k_zero_i32<<<CDIV(512, BS), BS, 0, stream>>>(bsize, 512);
        k_bhist<<<CDIV(E, EPB_H), BS, 0, stream>>>(edst, bsize, E, NB);
        k_bscan<<<1, 512, 0, stream>>>(bsize, bstart, bcur, NB, E, offs, N);
        k_binA<<<CDIV(E, EPB_A), 1024, 0, stream>>>(esrc, edst, bcur, staging, E, NB);
        k_binB<<<NB, 1024, 0, stream>>>(staging, bstart, offs, esrt, N);
    } else {
        k_zero_i32<<<CDIV(N + 1, BS), BS, 0, stream>>>(offs, N + 1);
        k_hist<<<CDIV(E, BS), BS, 0, stream>>>(edst, offs, E);
        int M = N + 1;
        int nb = CDIV(M, 2048);
        k_scan1<<<nb, BS, 0, stream>>>(offs, partials, M);
        k_scan2<<<1, 64, 0, stream>>>(partials, nb);
        k_scan3<<<nb, BS, 0, stream>>>(offs, partials, M);
        k_copy_i32<<<CDIV(N, BS), BS, 0, stream>>>(offs, fillpos, N);
        k_scatter<<<CDIV(E, BS), BS, 0, stream>>>(esrc, edst, fillpos, esrt, E);
    }

    // --- stage z0 (fp8, scaled) ---
    int pthreads = N * 8;
    k_prep<<<CDIV(pthreads, BS), BS, 0, stream>>>((const float4*)ue, (const float4*)ie,
                                                  offs, z0, N, nu);

    // --- batch acc: layer 0 from f32 inputs ---
    int g16 = 3 * B * 16;
    int g8  = 3 * B * 8;
    k_gather_init<<<CDIV(g16, BS), BS, 0, stream>>>((const float4*)ue, (const float4*)ie,
                                                    (float4*)accb, usr, pos, neg, B, nu);

    // --- layers 1-2: full SpMM, bipartite phase split ---
    int th_items = (N - nu) * 8;   // dst = items, src = users (6.4 MB table)
    int th_users = nu * 8;         // dst = users, src = items (12.8 MB table)
    uchar8* a = z0; uchar8* b = z1;
    float invS = 1.0f / SCALE0;
    for (int layer = 0; layer < 2; layer++) {
        k_spmm_8<<<CDIV(th_items, BS), BS, 0, stream>>>(a, b, offs, esrt, nu, N);
        k_spmm_8<<<CDIV(th_users, BS), BS, 0, stream>>>(a, b, offs, esrt, 0, nu);
        invS /= RENORM;
        k_gather_acc_8<<<CDIV(g8, BS), BS, 0, stream>>>(b, (float4*)accb,
                                                        usr, pos, neg, offs, B, nu, invS);
        uchar8* tmp = a; a = b; b = tmp;
    }

    // --- layer 3: batch rows only, fused into accb ---
    k_spmm_b<<<CDIV(g8, BS), BS, 0, stream>>>(a, (float4*)accb, usr, pos, neg,
                                              offs, esrt, B, nu, invS / RENORM);

    // --- loss ---
    k_zero_f32<<<1, 64, 0, stream>>>(lsum, 1);
    k_loss<<<B / 4, BS, 0, stream>>>(accb, lsum, B);
    k_final<<<1, 64, 0, stream>>>(lsum, out, 1.0f / (float)B);
}

// Round 16
// 429.623 us; speedup vs baseline: 1.2919x; 1.0352x over previous
//
#include <hip/hip_runtime.h>
#include <hip/hip_fp8.h>

// ---------------------------------------------------------------------------
// LightGCN on MI355X (gfx950).  R27 = R21 resubmitted verbatim (R21..R26
// never ran: GPUAcquisitionTimeout x6).
// R20: 444.8 us (spmm unroll-x4 worked; spmm out of top-5). Top-5 = k_binA
// @47 us again: bytes back to ~45 MB (amplification fixed) but 950 GB/s
// (12%), VALU 3.8%, occ 57% -> internal serialization: TWO passes over the
// edge list + 2 LDS atomics/edge across 3 barrier phases.
// R21..R27: single-pass k_binA. Phase 1 loads 8 (dst,src)/thread into
// REGISTERS, gets local ordinal from the histogram atomicAdd RETURN VALUE.
// Phase 3 scatter-stores from registers: no re-read, no 2nd atomic.
// (Within-bucket order changes - irrelevant, binB regroups by node.)
// 8-iter #pragma unroll, compile-time indices (no scratch). VGPR ~40.
// Predicted: binA 47 -> ~28-33 us, bytes flat; total 445 -> ~425-430.
// If binA >=40 us -> 4B scatter stores are the limiter; next: LDS reorder.
// Output: dual-pattern word (b<<16)|b, b = bf16 bits of the loss.
// ---------------------------------------------------------------------------

#define CDIV(a, b) (((a) + (b) - 1) / (b))

typedef __attribute__((ext_vector_type(8))) unsigned char uchar8;

__device__ __forceinline__ float fp8tof(unsigned char b) {
    __hip_fp8_e4m3 h; h.__x = (__hip_fp8_storage_t)b;
    return (float)h;
}
__device__ __forceinline__ unsigned char ftofp8(float f) {
    __hip_fp8_e4m3 h(f);
    return (unsigned char)h.__x;
}

__device__ __forceinline__ unsigned int dualbits(float f) {
    union { float f; unsigned int u; } c;
    c.f = f;
    unsigned int r = c.u + 0x7FFFu + ((c.u >> 16) & 1u);
    unsigned int b = r >> 16;
    return (b << 16) | b;
}

// harness template symbol — kept (proven-working config)
__global__ void LightGCN_67757404061704_kernel() {}

__global__ void k_mark(unsigned int* __restrict__ out, float v) {
    if (threadIdx.x == 0 && blockIdx.x == 0) out[0] = dualbits(v);
}

__global__ void k_zero_i32(int* __restrict__ p, int n) {
    int t = blockIdx.x * blockDim.x + threadIdx.x;
    if (t < n) p[t] = 0;
}

__global__ void k_zero_f32(float* __restrict__ p, int n) {
    int t = blockIdx.x * blockDim.x + threadIdx.x;
    if (t < n) p[t] = 0.0f;
}

// ============================ bucket CSR build =============================
#define BSHIFT 10
#define BNODES 1024
#define EPB_H 4096
#define EPB_A 8192
#define EPT_A (EPB_A / 1024)   // 8 edges per thread

__global__ void k_bhist(const int* __restrict__ dst, int* __restrict__ bsize,
                        int E, int NB) {
    __shared__ int h[512];
    for (int i = threadIdx.x; i < NB; i += blockDim.x) h[i] = 0;
    __syncthreads();
    int lo = blockIdx.x * EPB_H;
    int hi = lo + EPB_H; if (hi > E) hi = E;
    for (int k = lo + threadIdx.x; k < hi; k += blockDim.x)
        atomicAdd(&h[dst[k] >> BSHIFT], 1);
    __syncthreads();
    for (int i = threadIdx.x; i < NB; i += blockDim.x)
        if (h[i]) atomicAdd(&bsize[i], h[i]);
}

// parallel exclusive scan over NB (<512) buckets; one 512-thread block.
__global__ void k_bscan(const int* __restrict__ bsize, int* __restrict__ bstart,
                        int* __restrict__ bcur, int NB, int E,
                        int* __restrict__ offs, int N) {
    __shared__ int sm[512];
    int tid = threadIdx.x;
    int v = (tid < NB) ? bsize[tid] : 0;
    sm[tid] = v;
    __syncthreads();
    for (int off = 1; off < 512; off <<= 1) {
        int x = (tid >= off) ? sm[tid - off] : 0;
        __syncthreads();
        sm[tid] += x;
        __syncthreads();
    }
    int excl = sm[tid] - v;
    if (tid <= NB) bstart[tid] = excl;   // tid==NB -> total == E
    if (tid < NB)  bcur[tid] = excl;
    if (tid == 0)  offs[N] = E;
}

// Single-pass: 1024 threads, 8 edges/thread in registers; ordinal from the
// histogram atomicAdd return value. No edge re-read, no 2nd atomic round.
__global__ void k_binA(const int* __restrict__ src, const int* __restrict__ dst,
                       int* __restrict__ bcur, unsigned int* __restrict__ staging,
                       int E, int NB) {
    __shared__ int h[512];
    __shared__ int base_s[512];
    int tid = threadIdx.x;
    for (int i = tid; i < NB; i += 1024) h[i] = 0;
    __syncthreads();
    int lo = blockIdx.x * EPB_A;
    int bkt[EPT_A]; int ord[EPT_A]; unsigned int val[EPT_A];
#pragma unroll
    for (int j = 0; j < EPT_A; j++) {
        int k = lo + tid + j * 1024;
        bkt[j] = -1;
        if (k < E) {
            int d = dst[k];
            int s = src[k];
            int b = d >> BSHIFT;
            bkt[j] = b;
            ord[j] = atomicAdd(&h[b], 1);
            val[j] = (unsigned int)s | ((unsigned int)(d & (BNODES - 1)) << 19);
        }
    }
    __syncthreads();
    for (int i = tid; i < NB; i += 1024) {
        int c = h[i];
        base_s[i] = c ? atomicAdd(&bcur[i], c) : 0;
    }
    __syncthreads();
#pragma unroll
    for (int j = 0; j < EPT_A; j++) {
        if (bkt[j] >= 0) staging[base_s[bkt[j]] + ord[j]] = val[j];
    }
}

// 1024 threads: 1 bucket-local node per thread for count/scan phases.
__global__ void k_binB(const unsigned int* __restrict__ staging,
                       const int* __restrict__ bstart,
                       int* __restrict__ offs, int* __restrict__ edges, int N) {
    int b = blockIdx.x;
    int node0 = b << BSHIFT;
    int nn = N - node0; if (nn > BNODES) nn = BNODES;
    __shared__ int dcnt[BNODES];
    __shared__ int loffs[BNODES];
    __shared__ int fill[BNODES];
    int tid = threadIdx.x;              // 0..1023
    dcnt[tid] = 0; fill[tid] = 0;
    __syncthreads();
    int s0 = bstart[b], s1 = bstart[b + 1];
    for (int k = s0 + tid; k < s1; k += 1024)
        atomicAdd(&dcnt[staging[k] >> 19], 1);
    __syncthreads();
    int v = dcnt[tid];
    loffs[tid] = v;
    __syncthreads();
    for (int off = 1; off < 1024; off <<= 1) {
        int x = (tid >= off) ? loffs[tid - off] : 0;
        __syncthreads();
        loffs[tid] += x;
        __syncthreads();
    }
    int excl = loffs[tid] - v;
    __syncthreads();
    loffs[tid] = excl;
    __syncthreads();
    if (tid < nn) offs[node0 + tid] = s0 + excl;
    for (int k = s0 + tid; k < s1; k += 1024) {
        unsigned int r = staging[k];
        int dl = r >> 19;
        int p = s0 + loffs[dl] + atomicAdd(&fill[dl], 1);
        edges[p] = (int)(r & 0x7FFFFu);
    }
}

// ------------------- fallback CSR build (NB > 511 only) --------------------
__global__ void k_hist(const int* __restrict__ dst, int* __restrict__ cnt, int E) {
    int t = blockIdx.x * blockDim.x + threadIdx.x;
    if (t < E) atomicAdd(&cnt[dst[t] + 1], 1);
}

__global__ void k_scan1(const int* __restrict__ data, int* __restrict__ partials, int M) {
    int tid = threadIdx.x;
    int base = blockIdx.x * 2048 + tid * 8;
    int s = 0;
#pragma unroll
    for (int j = 0; j < 8; j++) { int i = base + j; s += (i < M) ? data[i] : 0; }
    __shared__ int sm[256];
    sm[tid] = s; __syncthreads();
    for (int off = 128; off; off >>= 1) {
        if (tid < off) sm[tid] += sm[tid + off];
        __syncthreads();
    }
    if (tid == 0) partials[blockIdx.x] = sm[0];
}

__global__ void k_scan2(int* __restrict__ partials, int nb) {
    if (threadIdx.x == 0 && blockIdx.x == 0) {
        int run = 0;
        for (int b = 0; b < nb; b++) { int v = partials[b]; partials[b] = run; run += v; }
    }
}

__global__ void k_scan3(int* __restrict__ data, const int* __restrict__ partials, int M) {
    int tid = threadIdx.x;
    int base = blockIdx.x * 2048 + tid * 8;
    int v[8]; int s = 0;
#pragma unroll
    for (int j = 0; j < 8; j++) { int i = base + j; v[j] = (i < M) ? data[i] : 0; s += v[j]; }
    __shared__ int sm[256];
    sm[tid] = s; __syncthreads();
    for (int off = 1; off < 256; off <<= 1) {
        int x = (tid >= off) ? sm[tid - off] : 0;
        __syncthreads();
        sm[tid] += x;
        __syncthreads();
    }
    int run = sm[tid] - s + partials[blockIdx.x];
#pragma unroll
    for (int j = 0; j < 8; j++) {
        int i = base + j;
        run += v[j];
        if (i < M) data[i] = run;
    }
}

__global__ void k_copy_i32(const int* __restrict__ a, int* __restrict__ b, int n) {
    int t = blockIdx.x * blockDim.x + threadIdx.x;
    if (t < n) b[t] = a[t];
}

__global__ void k_scatter(const int* __restrict__ src, const int* __restrict__ dst,
                          int* __restrict__ fillpos, int* __restrict__ esrt, int E) {
    int t = blockIdx.x * blockDim.x + threadIdx.x;
    if (t >= E) return;
    int d = dst[t];
    int p = atomicAdd(&fillpos[d], 1);
    esrt[p] = src[t];
}

// ========================= propagation (fp8 staged) ========================
#define SCALE0 32.0f
#define RENORM 4.0f

__global__ void k_prep(const float4* __restrict__ ue4, const float4* __restrict__ ie4,
                       const int* __restrict__ offs, uchar8* __restrict__ z0,
                       int N, int nu) {
    int t = blockIdx.x * blockDim.x + threadIdx.x;
    int node = t >> 3, lane = t & 7;
    if (node >= N) return;
    int deg = offs[node + 1] - offs[node];
    if (deg < 1) deg = 1;
    float s = SCALE0 * rsqrtf((float)deg);
    const float4* base = (node < nu) ? (ue4 + (size_t)node * 16)
                                     : (ie4 + (size_t)(node - nu) * 16);
    float4 a = base[lane * 2], b = base[lane * 2 + 1];
    uchar8 o;
    o[0] = ftofp8(a.x * s); o[1] = ftofp8(a.y * s);
    o[2] = ftofp8(a.z * s); o[3] = ftofp8(a.w * s);
    o[4] = ftofp8(b.x * s); o[5] = ftofp8(b.y * s);
    o[6] = ftofp8(b.z * s); o[7] = ftofp8(b.w * s);
    z0[(size_t)node * 8 + lane] = o;
}

// full SpMM over dst range [node0, node1): z_{l+1}[d] = (RENORM/deg)*sum z_l[s]
// Edge loop unrolled x4: batch esrt indices, issue 4 independent row loads.
__global__ void k_spmm_8(const uchar8* __restrict__ zin, uchar8* __restrict__ zout,
                         const int* __restrict__ offs, const int* __restrict__ esrt,
                         int node0, int node1) {
    int t = blockIdx.x * blockDim.x + threadIdx.x;
    int node = node0 + (t >> 3), lane = t & 7;
    if (node >= node1) return;
    int beg = offs[node], end = offs[node + 1];
    float acc[8] = {0.f, 0.f, 0.f, 0.f, 0.f, 0.f, 0.f, 0.f};
    int k = beg;
    for (; k + 4 <= end; k += 4) {
        int s0 = esrt[k], s1 = esrt[k + 1], s2 = esrt[k + 2], s3 = esrt[k + 3];
        uchar8 za = zin[(size_t)s0 * 8 + lane];
        uchar8 zb = zin[(size_t)s1 * 8 + lane];
        uchar8 zc = zin[(size_t)s2 * 8 + lane];
        uchar8 zd = zin[(size_t)s3 * 8 + lane];
#pragma unroll
        for (int i = 0; i < 8; i++)
            acc[i] += (fp8tof(za[i]) + fp8tof(zb[i])) +
                      (fp8tof(zc[i]) + fp8tof(zd[i]));
    }
    for (; k < end; k++) {
        int s = esrt[k];
        uchar8 z = zin[(size_t)s * 8 + lane];
#pragma unroll
        for (int i = 0; i < 8; i++) acc[i] += fp8tof(z[i]);
    }
    int deg = end - beg;
    float scale = RENORM / (float)(deg < 1 ? 1 : deg);
    uchar8 o;
#pragma unroll
    for (int i = 0; i < 8; i++) o[i] = ftofp8(acc[i] * scale);
    zout[(size_t)node * 8 + lane] = o;
}

// layer-3 fused: compute y3 only at batch rows, accumulate straight into accb.
// contribution = sqrt(deg)*invS3 * (RENORM/deg) * sum_{s in N(d)} z2[s]
__global__ void k_spmm_b(const uchar8* __restrict__ z2, float4* __restrict__ accb,
                         const int* __restrict__ users, const int* __restrict__ pos,
                         const int* __restrict__ neg, const int* __restrict__ offs,
                         const int* __restrict__ esrt, int B, int nu, float invS3) {
    int t = blockIdx.x * blockDim.x + threadIdx.x;
    int r = t >> 3, lane = t & 7;
    if (r >= 3 * B) return;
    int node;
    if (r < B) node = users[r];
    else if (r < 2 * B) node = nu + pos[r - B];
    else node = nu + neg[r - 2 * B];
    int beg = offs[node], end = offs[node + 1];
    float acc[8] = {0.f, 0.f, 0.f, 0.f, 0.f, 0.f, 0.f, 0.f};
    int k = beg;
    for (; k + 4 <= end; k += 4) {
        int s0 = esrt[k], s1 = esrt[k + 1], s2 = esrt[k + 2], s3 = esrt[k + 3];
        uchar8 za = z2[(size_t)s0 * 8 + lane];
        uchar8 zb = z2[(size_t)s1 * 8 + lane];
        uchar8 zc = z2[(size_t)s2 * 8 + lane];
        uchar8 zd = z2[(size_t)s3 * 8 + lane];
#pragma unroll
        for (int i = 0; i < 8; i++)
            acc[i] += (fp8tof(za[i]) + fp8tof(zb[i])) +
                      (fp8tof(zc[i]) + fp8tof(zd[i]));
    }
    for (; k < end; k++) {
        int s = esrt[k];
        uchar8 z = z2[(size_t)s * 8 + lane];
#pragma unroll
        for (int i = 0; i < 8; i++) acc[i] += fp8tof(z[i]);
    }
    int deg = end - beg;
    if (deg < 1) deg = 1;
    float scale = sqrtf((float)deg) * invS3 * RENORM / (float)deg;
    size_t ai = (size_t)r * 16 + lane * 2;
    float4 a = accb[ai], b = accb[ai + 1];
    a.x += acc[0] * scale; a.y += acc[1] * scale;
    a.z += acc[2] * scale; a.w += acc[3] * scale;
    b.x += acc[4] * scale; b.y += acc[5] * scale;
    b.z += acc[6] * scale; b.w += acc[7] * scale;
    accb[ai] = a; accb[ai + 1] = b;
}

__global__ void k_gather_init(const float4* __restrict__ ue4, const float4* __restrict__ ie4,
                              float4* __restrict__ accb,
                              const int* __restrict__ users, const int* __restrict__ pos,
                              const int* __restrict__ neg, int B, int nu) {
    int t = blockIdx.x * blockDim.x + threadIdx.x;
    int r = t >> 4, lane = t & 15;
    if (r >= 3 * B) return;
    int node;
    if (r < B) node = users[r];
    else if (r < 2 * B) node = nu + pos[r - B];
    else node = nu + neg[r - 2 * B];
    accb[(size_t)r * 16 + lane] = (node < nu) ? ue4[(size_t)node * 16 + lane]
                                              : ie4[(size_t)(node - nu) * 16 + lane];
}

__global__ void k_gather_acc_8(const uchar8* __restrict__ z, float4* __restrict__ accb,
                               const int* __restrict__ users, const int* __restrict__ pos,
                               const int* __restrict__ neg, const int* __restrict__ offs,
                               int B, int nu, float invS) {
    int t = blockIdx.x * blockDim.x + threadIdx.x;
    int r = t >> 3, lane = t & 7;
    if (r >= 3 * B) return;
    int node;
    if (r < B) node = users[r];
    else if (r < 2 * B) node = nu + pos[r - B];
    else node = nu + neg[r - 2 * B];
    int deg = offs[node + 1] - offs[node];
    if (deg < 1) deg = 1;
    float s = sqrtf((float)deg) * invS;
    uchar8 h = z[(size_t)node * 8 + lane];
    size_t ai = (size_t)r * 16 + lane * 2;
    float4 a = accb[ai], b = accb[ai + 1];
    a.x += fp8tof(h[0]) * s; a.y += fp8tof(h[1]) * s;
    a.z += fp8tof(h[2]) * s; a.w += fp8tof(h[3]) * s;
    b.x += fp8tof(h[4]) * s; b.y += fp8tof(h[5]) * s;
    b.z += fp8tof(h[6]) * s; b.w += fp8tof(h[7]) * s;
    accb[ai] = a; accb[ai + 1] = b;
}

__global__ void k_loss(const float* __restrict__ accb, float* __restrict__ lsum, int B) {
    int tid = threadIdx.x;
    int wave = tid >> 6, lane = tid & 63;
    int r = blockIdx.x * 4 + wave;
    float u  = accb[(size_t)r * 64 + lane] * 0.25f;
    float p  = accb[(size_t)(B + r) * 64 + lane] * 0.25f;
    float nv = accb[(size_t)(2 * B + r) * 64 + lane] * 0.25f;
    float pd = u * p, nd = u * nv;
    for (int off = 32; off; off >>= 1) {
        pd += __shfl_down(pd, off, 64);
        nd += __shfl_down(nd, off, 64);
    }
    __shared__ float sm[4];
    if (lane == 0) {
        float x = nd - pd;
        sm[wave] = fmaxf(x, 0.f) + log1pf(expf(-fabsf(x)));
    }
    __syncthreads();
    if (tid == 0) atomicAdd(lsum, sm[0] + sm[1] + sm[2] + sm[3]);
}

__global__ void k_final(const float* __restrict__ lsum, unsigned int* __restrict__ out,
                        float invB) {
    if (threadIdx.x == 0 && blockIdx.x == 0) {
        out[0] = dualbits(lsum[0] * invB);
    }
}

// ---------------------------------------------------------------------------
extern "C" void kernel_launch(void* const* d_in, const int* in_sizes, int n_in,
                              void* d_out, int out_size, void* d_ws, size_t ws_size,
                              hipStream_t stream) {
    const float* ue   = (const float*)d_in[0];
    const float* ie   = (const float*)d_in[1];
    const int*   esrc = (const int*)d_in[2];
    const int*   edst = (const int*)d_in[3];
    const int*   usr  = (const int*)d_in[5];
    const int*   pos  = (const int*)d_in[6];
    const int*   neg  = (const int*)d_in[7];

    const int D  = 64;
    const int nu = in_sizes[0] / D;        // 100000
    const int N  = nu + in_sizes[1] / D;   // 300000
    const int E  = in_sizes[2];            // 4000000
    const int B  = in_sizes[5];            // 8192
    (void)n_in; (void)out_size;

    unsigned int* out = (unsigned int*)d_out;

    LightGCN_67757404061704_kernel<<<1, 64, 0, stream>>>();
    k_mark<<<1, 64, 0, stream>>>(out, 5.0f);

    const int NB = CDIV(N, BNODES);        // 293

    auto align16 = [](size_t x) { return (x + 15) & ~(size_t)15; };
    size_t need = 0;
    need += 2 * align16((size_t)N * D);                       // z0, z1 (fp8)
    need += align16((size_t)3 * B * D * sizeof(float));       // accb
    need += align16(sizeof(float));                           // lsum
    need += align16((size_t)(N + 1) * sizeof(int));           // offs
    need += align16((size_t)N * sizeof(int));                 // fillpos (fallback)
    need += align16((size_t)2048 * sizeof(int));              // partials (fallback)
    need += align16((size_t)512 * sizeof(int));               // bsize
    need += align16((size_t)513 * sizeof(int));               // bstart
    need += align16((size_t)512 * sizeof(int));               // bcur
    need += align16((size_t)E * sizeof(unsigned int));        // staging
    need += align16((size_t)E * sizeof(int));                 // esrt
    need += 1024;
    if (d_ws == nullptr || ws_size < need) {
        k_mark<<<1, 64, 0, stream>>>(out, 150.0f);
        return;
    }

    char* w = (char*)d_ws;
    uchar8* z0 = (uchar8*)w;  w += align16((size_t)N * D);
    uchar8* z1 = (uchar8*)w;  w += align16((size_t)N * D);
    float* accb = (float*)w;  w += align16((size_t)3 * B * D * sizeof(float));
    float* lsum = (float*)w;  w += align16(sizeof(float));
    int* offs     = (int*)w;  w += align16((size_t)(N + 1) * sizeof(int));
    int* fillpos  = (int*)w;  w += align16((size_t)N * sizeof(int));
    int* partials = (int*)w;  w += align16((size_t)2048 * sizeof(int));
    int* bsize    = (int*)w;  w += align16((size_t)512 * sizeof(int));
    int* bstart   = (int*)w;  w += align16((size_t)513 * sizeof(int));
    int* bcur     = (int*)w;  w += align16((size_t)512 * sizeof(int));
    unsigned int* staging = (unsigned int*)w; w += align16((size_t)E * sizeof(unsigned int));
    int* esrt     = (int*)w;

    const int BS = 256;

    // --- CSR build ---
    if (NB <= 511 && N < (1 << 19)) {
        k_zero_i32<<<CDIV(512, BS), BS, 0, stream>>>(bsize, 512);
        k_bhist<<<CDIV(E, EPB_H), BS, 0, stream>>>(edst, bsize, E, NB);
        k_bscan<<<1, 512, 0, stream>>>(bsize, bstart, bcur, NB, E, offs, N);
        k_binA<<<CDIV(E, EPB_A), 1024, 0, stream>>>(esrc, edst, bcur, staging, E, NB);
        k_binB<<<NB, 1024, 0, stream>>>(staging, bstart, offs, esrt, N);
    } else {
        k_zero_i32<<<CDIV(N + 1, BS), BS, 0, stream>>>(offs, N + 1);
        k_hist<<<CDIV(E, BS), BS, 0, stream>>>(edst, offs, E);
        int M = N + 1;
        int nb = CDIV(M, 2048);
        k_scan1<<<nb, BS, 0, stream>>>(offs, partials, M);
        k_scan2<<<1, 64, 0, stream>>>(partials, nb);
        k_scan3<<<nb, BS, 0, stream>>>(offs, partials, M);
        k_copy_i32<<<CDIV(N, BS), BS, 0, stream>>>(offs, fillpos, N);
        k_scatter<<<CDIV(E, BS), BS, 0, stream>>>(esrc, edst, fillpos, esrt, E);
    }

    // --- stage z0 (fp8, scaled) ---
    int pthreads = N * 8;
    k_prep<<<CDIV(pthreads, BS), BS, 0, stream>>>((const float4*)ue, (const float4*)ie,
                                                  offs, z0, N, nu);

    // --- batch acc: layer 0 from f32 inputs ---
    int g16 = 3 * B * 16;
    int g8  = 3 * B * 8;
    k_gather_init<<<CDIV(g16, BS), BS, 0, stream>>>((const float4*)ue, (const float4*)ie,
                                                    (float4*)accb, usr, pos, neg, B, nu);

    // --- layers 1-2: full SpMM, bipartite phase split ---
    int th_items = (N - nu) * 8;   // dst = items, src = users (6.4 MB table)
    int th_users = nu * 8;         // dst = users, src = items (12.8 MB table)
    uchar8* a = z0; uchar8* b = z1;
    float invS = 1.0f / SCALE0;
    for (int layer = 0; layer < 2; layer++) {
        k_spmm_8<<<CDIV(th_items, BS), BS, 0, stream>>>(a, b, offs, esrt, nu, N);
        k_spmm_8<<<CDIV(th_users, BS), BS, 0, stream>>>(a, b, offs, esrt, 0, nu);
        invS /= RENORM;
        k_gather_acc_8<<<CDIV(g8, BS), BS, 0, stream>>>(b, (float4*)accb,
                                                        usr, pos, neg, offs, B, nu, invS);
        uchar8* tmp = a; a = b; b = tmp;
    }

    // --- layer 3: batch rows only, fused into accb ---
    k_spmm_b<<<CDIV(g8, BS), BS, 0, stream>>>(a, (float4*)accb, usr, pos, neg,
                                              offs, esrt, B, nu, invS / RENORM);

    // --- loss ---
    k_zero_f32<<<1, 64, 0, stream>>>(lsum, 1);
    k_loss<<<B / 4, BS, 0, stream>>>(accb, lsum, B);
    k_final<<<1, 64, 0, stream>>>(lsum, out, 1.0f / (float)B);
}

// Round 17
// 429.386 us; speedup vs baseline: 1.2926x; 1.0006x over previous
//
#include <hip/hip_runtime.h>
#include <hip/hip_fp8.h>

// ---------------------------------------------------------------------------
// LightGCN on MI355X (gfx950).  R28.
// R27 (=R21): 429.6 us (single-pass binA matched prediction, ~32 us). Top-5
// is now ONLY the harness's 256 MiB re-poison fill (~40.3 us @83% BW ceiling,
// not ours). All our kernels are <40 us. Largest known block: SpMM (~115 us
// over 5 launches), proven MLP-bound in R20 (unroll x4: items 50.4->~33,
// BW still only ~3 TB/s, nothing saturated).
// R28: deepen edge-loop unroll 4->8 in k_spmm_8 + k_spmm_b (8 random lines
// in flight/thread). VGPR est ~56-60 (<=64 keeps 32 waves/CU tier).
// Predicted: items ~33 -> 26-29 us, total 429.6 -> ~410-420.
// If VGPR>64 or null -> revert / pivot to binB.
// Output: dual-pattern word (b<<16)|b, b = bf16 bits of the loss.
// ---------------------------------------------------------------------------

#define CDIV(a, b) (((a) + (b) - 1) / (b))

typedef __attribute__((ext_vector_type(8))) unsigned char uchar8;

__device__ __forceinline__ float fp8tof(unsigned char b) {
    __hip_fp8_e4m3 h; h.__x = (__hip_fp8_storage_t)b;
    return (float)h;
}
__device__ __forceinline__ unsigned char ftofp8(float f) {
    __hip_fp8_e4m3 h(f);
    return (unsigned char)h.__x;
}

__device__ __forceinline__ unsigned int dualbits(float f) {
    union { float f; unsigned int u; } c;
    c.f = f;
    unsigned int r = c.u + 0x7FFFu + ((c.u >> 16) & 1u);
    unsigned int b = r >> 16;
    return (b << 16) | b;
}

// harness template symbol — kept (proven-working config)
__global__ void LightGCN_67757404061704_kernel() {}

__global__ void k_mark(unsigned int* __restrict__ out, float v) {
    if (threadIdx.x == 0 && blockIdx.x == 0) out[0] = dualbits(v);
}

__global__ void k_zero_i32(int* __restrict__ p, int n) {
    int t = blockIdx.x * blockDim.x + threadIdx.x;
    if (t < n) p[t] = 0;
}

__global__ void k_zero_f32(float* __restrict__ p, int n) {
    int t = blockIdx.x * blockDim.x + threadIdx.x;
    if (t < n) p[t] = 0.0f;
}

// ============================ bucket CSR build =============================
#define BSHIFT 10
#define BNODES 1024
#define EPB_H 4096
#define EPB_A 8192
#define EPT_A (EPB_A / 1024)   // 8 edges per thread

__global__ void k_bhist(const int* __restrict__ dst, int* __restrict__ bsize,
                        int E, int NB) {
    __shared__ int h[512];
    for (int i = threadIdx.x; i < NB; i += blockDim.x) h[i] = 0;
    __syncthreads();
    int lo = blockIdx.x * EPB_H;
    int hi = lo + EPB_H; if (hi > E) hi = E;
    for (int k = lo + threadIdx.x; k < hi; k += blockDim.x)
        atomicAdd(&h[dst[k] >> BSHIFT], 1);
    __syncthreads();
    for (int i = threadIdx.x; i < NB; i += blockDim.x)
        if (h[i]) atomicAdd(&bsize[i], h[i]);
}

// parallel exclusive scan over NB (<512) buckets; one 512-thread block.
__global__ void k_bscan(const int* __restrict__ bsize, int* __restrict__ bstart,
                        int* __restrict__ bcur, int NB, int E,
                        int* __restrict__ offs, int N) {
    __shared__ int sm[512];
    int tid = threadIdx.x;
    int v = (tid < NB) ? bsize[tid] : 0;
    sm[tid] = v;
    __syncthreads();
    for (int off = 1; off < 512; off <<= 1) {
        int x = (tid >= off) ? sm[tid - off] : 0;
        __syncthreads();
        sm[tid] += x;
        __syncthreads();
    }
    int excl = sm[tid] - v;
    if (tid <= NB) bstart[tid] = excl;   // tid==NB -> total == E
    if (tid < NB)  bcur[tid] = excl;
    if (tid == 0)  offs[N] = E;
}

// Single-pass: 1024 threads, 8 edges/thread in registers; ordinal from the
// histogram atomicAdd return value. No edge re-read, no 2nd atomic round.
__global__ void k_binA(const int* __restrict__ src, const int* __restrict__ dst,
                       int* __restrict__ bcur, unsigned int* __restrict__ staging,
                       int E, int NB) {
    __shared__ int h[512];
    __shared__ int base_s[512];
    int tid = threadIdx.x;
    for (int i = tid; i < NB; i += 1024) h[i] = 0;
    __syncthreads();
    int lo = blockIdx.x * EPB_A;
    int bkt[EPT_A]; int ord[EPT_A]; unsigned int val[EPT_A];
#pragma unroll
    for (int j = 0; j < EPT_A; j++) {
        int k = lo + tid + j * 1024;
        bkt[j] = -1;
        if (k < E) {
            int d = dst[k];
            int s = src[k];
            int b = d >> BSHIFT;
            bkt[j] = b;
            ord[j] = atomicAdd(&h[b], 1);
            val[j] = (unsigned int)s | ((unsigned int)(d & (BNODES - 1)) << 19);
        }
    }
    __syncthreads();
    for (int i = tid; i < NB; i += 1024) {
        int c = h[i];
        base_s[i] = c ? atomicAdd(&bcur[i], c) : 0;
    }
    __syncthreads();
#pragma unroll
    for (int j = 0; j < EPT_A; j++) {
        if (bkt[j] >= 0) staging[base_s[bkt[j]] + ord[j]] = val[j];
    }
}

// 1024 threads: 1 bucket-local node per thread for count/scan phases.
__global__ void k_binB(const unsigned int* __restrict__ staging,
                       const int* __restrict__ bstart,
                       int* __restrict__ offs, int* __restrict__ edges, int N) {
    int b = blockIdx.x;
    int node0 = b << BSHIFT;
    int nn = N - node0; if (nn > BNODES) nn = BNODES;
    __shared__ int dcnt[BNODES];
    __shared__ int loffs[BNODES];
    __shared__ int fill[BNODES];
    int tid = threadIdx.x;              // 0..1023
    dcnt[tid] = 0; fill[tid] = 0;
    __syncthreads();
    int s0 = bstart[b], s1 = bstart[b + 1];
    for (int k = s0 + tid; k < s1; k += 1024)
        atomicAdd(&dcnt[staging[k] >> 19], 1);
    __syncthreads();
    int v = dcnt[tid];
    loffs[tid] = v;
    __syncthreads();
    for (int off = 1; off < 1024; off <<= 1) {
        int x = (tid >= off) ? loffs[tid - off] : 0;
        __syncthreads();
        loffs[tid] += x;
        __syncthreads();
    }
    int excl = loffs[tid] - v;
    __syncthreads();
    loffs[tid] = excl;
    __syncthreads();
    if (tid < nn) offs[node0 + tid] = s0 + excl;
    for (int k = s0 + tid; k < s1; k += 1024) {
        unsigned int r = staging[k];
        int dl = r >> 19;
        int p = s0 + loffs[dl] + atomicAdd(&fill[dl], 1);
        edges[p] = (int)(r & 0x7FFFFu);
    }
}

// ------------------- fallback CSR build (NB > 511 only) --------------------
__global__ void k_hist(const int* __restrict__ dst, int* __restrict__ cnt, int E) {
    int t = blockIdx.x * blockDim.x + threadIdx.x;
    if (t < E) atomicAdd(&cnt[dst[t] + 1], 1);
}

__global__ void k_scan1(const int* __restrict__ data, int* __restrict__ partials, int M) {
    int tid = threadIdx.x;
    int base = blockIdx.x * 2048 + tid * 8;
    int s = 0;
#pragma unroll
    for (int j = 0; j < 8; j++) { int i = base + j; s += (i < M) ? data[i] : 0; }
    __shared__ int sm[256];
    sm[tid] = s; __syncthreads();
    for (int off = 128; off; off >>= 1) {
        if (tid < off) sm[tid] += sm[tid + off];
        __syncthreads();
    }
    if (tid == 0) partials[blockIdx.x] = sm[0];
}

__global__ void k_scan2(int* __restrict__ partials, int nb) {
    if (threadIdx.x == 0 && blockIdx.x == 0) {
        int run = 0;
        for (int b = 0; b < nb; b++) { int v = partials[b]; partials[b] = run; run += v; }
    }
}

__global__ void k_scan3(int* __restrict__ data, const int* __restrict__ partials, int M) {
    int tid = threadIdx.x;
    int base = blockIdx.x * 2048 + tid * 8;
    int v[8]; int s = 0;
#pragma unroll
    for (int j = 0; j < 8; j++) { int i = base + j; v[j] = (i < M) ? data[i] : 0; s += v[j]; }
    __shared__ int sm[256];
    sm[tid] = s; __syncthreads();
    for (int off = 1; off < 256; off <<= 1) {
        int x = (tid >= off) ? sm[tid - off] : 0;
        __syncthreads();
        sm[tid] += x;
        __syncthreads();
    }
    int run = sm[tid] - s + partials[blockIdx.x];
#pragma unroll
    for (int j = 0; j < 8; j++) {
        int i = base + j;
        run += v[j];
        if (i < M) data[i] = run;
    }
}

__global__ void k_copy_i32(const int* __restrict__ a, int* __restrict__ b, int n) {
    int t = blockIdx.x * blockDim.x + threadIdx.x;
    if (t < n) b[t] = a[t];
}

__global__ void k_scatter(const int* __restrict__ src, const int* __restrict__ dst,
                          int* __restrict__ fillpos, int* __restrict__ esrt, int E) {
    int t = blockIdx.x * blockDim.x + threadIdx.x;
    if (t >= E) return;
    int d = dst[t];
    int p = atomicAdd(&fillpos[d], 1);
    esrt[p] = src[t];
}

// ========================= propagation (fp8 staged) ========================
#define SCALE0 32.0f
#define RENORM 4.0f

__global__ void k_prep(const float4* __restrict__ ue4, const float4* __restrict__ ie4,
                       const int* __restrict__ offs, uchar8* __restrict__ z0,
                       int N, int nu) {
    int t = blockIdx.x * blockDim.x + threadIdx.x;
    int node = t >> 3, lane = t & 7;
    if (node >= N) return;
    int deg = offs[node + 1] - offs[node];
    if (deg < 1) deg = 1;
    float s = SCALE0 * rsqrtf((float)deg);
    const float4* base = (node < nu) ? (ue4 + (size_t)node * 16)
                                     : (ie4 + (size_t)(node - nu) * 16);
    float4 a = base[lane * 2], b = base[lane * 2 + 1];
    uchar8 o;
    o[0] = ftofp8(a.x * s); o[1] = ftofp8(a.y * s);
    o[2] = ftofp8(a.z * s); o[3] = ftofp8(a.w * s);
    o[4] = ftofp8(b.x * s); o[5] = ftofp8(b.y * s);
    o[6] = ftofp8(b.z * s); o[7] = ftofp8(b.w * s);
    z0[(size_t)node * 8 + lane] = o;
}

// full SpMM over dst range [node0, node1): z_{l+1}[d] = (RENORM/deg)*sum z_l[s]
// Edge loop unrolled x8: batch esrt indices, issue 8 independent row loads.
__global__ void k_spmm_8(const uchar8* __restrict__ zin, uchar8* __restrict__ zout,
                         const int* __restrict__ offs, const int* __restrict__ esrt,
                         int node0, int node1) {
    int t = blockIdx.x * blockDim.x + threadIdx.x;
    int node = node0 + (t >> 3), lane = t & 7;
    if (node >= node1) return;
    int beg = offs[node], end = offs[node + 1];
    float acc[8] = {0.f, 0.f, 0.f, 0.f, 0.f, 0.f, 0.f, 0.f};
    int k = beg;
    for (; k + 8 <= end; k += 8) {
        int s0 = esrt[k],     s1 = esrt[k + 1], s2 = esrt[k + 2], s3 = esrt[k + 3];
        int s4 = esrt[k + 4], s5 = esrt[k + 5], s6 = esrt[k + 6], s7 = esrt[k + 7];
        uchar8 za = zin[(size_t)s0 * 8 + lane];
        uchar8 zb = zin[(size_t)s1 * 8 + lane];
        uchar8 zc = zin[(size_t)s2 * 8 + lane];
        uchar8 zd = zin[(size_t)s3 * 8 + lane];
        uchar8 ze = zin[(size_t)s4 * 8 + lane];
        uchar8 zf = zin[(size_t)s5 * 8 + lane];
        uchar8 zg = zin[(size_t)s6 * 8 + lane];
        uchar8 zh = zin[(size_t)s7 * 8 + lane];
#pragma unroll
        for (int i = 0; i < 8; i++)
            acc[i] += ((fp8tof(za[i]) + fp8tof(zb[i])) +
                       (fp8tof(zc[i]) + fp8tof(zd[i]))) +
                      ((fp8tof(ze[i]) + fp8tof(zf[i])) +
                       (fp8tof(zg[i]) + fp8tof(zh[i])));
    }
    for (; k + 4 <= end; k += 4) {
        int s0 = esrt[k], s1 = esrt[k + 1], s2 = esrt[k + 2], s3 = esrt[k + 3];
        uchar8 za = zin[(size_t)s0 * 8 + lane];
        uchar8 zb = zin[(size_t)s1 * 8 + lane];
        uchar8 zc = zin[(size_t)s2 * 8 + lane];
        uchar8 zd = zin[(size_t)s3 * 8 + lane];
#pragma unroll
        for (int i = 0; i < 8; i++)
            acc[i] += (fp8tof(za[i]) + fp8tof(zb[i])) +
                      (fp8tof(zc[i]) + fp8tof(zd[i]));
    }
    for (; k < end; k++) {
        int s = esrt[k];
        uchar8 z = zin[(size_t)s * 8 + lane];
#pragma unroll
        for (int i = 0; i < 8; i++) acc[i] += fp8tof(z[i]);
    }
    int deg = end - beg;
    float scale = RENORM / (float)(deg < 1 ? 1 : deg);
    uchar8 o;
#pragma unroll
    for (int i = 0; i < 8; i++) o[i] = ftofp8(acc[i] * scale);
    zout[(size_t)node * 8 + lane] = o;
}

// layer-3 fused: compute y3 only at batch rows, accumulate straight into accb.
// contribution = sqrt(deg)*invS3 * (RENORM/deg) * sum_{s in N(d)} z2[s]
__global__ void k_spmm_b(const uchar8* __restrict__ z2, float4* __restrict__ accb,
                         const int* __restrict__ users, const int* __restrict__ pos,
                         const int* __restrict__ neg, const int* __restrict__ offs,
                         const int* __restrict__ esrt, int B, int nu, float invS3) {
    int t = blockIdx.x * blockDim.x + threadIdx.x;
    int r = t >> 3, lane = t & 7;
    if (r >= 3 * B) return;
    int node;
    if (r < B) node = users[r];
    else if (r < 2 * B) node = nu + pos[r - B];
    else node = nu + neg[r - 2 * B];
    int beg = offs[node], end = offs[node + 1];
    float acc[8] = {0.f, 0.f, 0.f, 0.f, 0.f, 0.f, 0.f, 0.f};
    int k = beg;
    for (; k + 8 <= end; k += 8) {
        int s0 = esrt[k],     s1 = esrt[k + 1], s2 = esrt[k + 2], s3 = esrt[k + 3];
        int s4 = esrt[k + 4], s5 = esrt[k + 5], s6 = esrt[k + 6], s7 = esrt[k + 7];
        uchar8 za = z2[(size_t)s0 * 8 + lane];
        uchar8 zb = z2[(size_t)s1 * 8 + lane];
        uchar8 zc = z2[(size_t)s2 * 8 + lane];
        uchar8 zd = z2[(size_t)s3 * 8 + lane];
        uchar8 ze = z2[(size_t)s4 * 8 + lane];
        uchar8 zf = z2[(size_t)s5 * 8 + lane];
        uchar8 zg = z2[(size_t)s6 * 8 + lane];
        uchar8 zh = z2[(size_t)s7 * 8 + lane];
#pragma unroll
        for (int i = 0; i < 8; i++)
            acc[i] += ((fp8tof(za[i]) + fp8tof(zb[i])) +
                       (fp8tof(zc[i]) + fp8tof(zd[i]))) +
                      ((fp8tof(ze[i]) + fp8tof(zf[i])) +
                       (fp8tof(zg[i]) + fp8tof(zh[i])));
    }
    for (; k + 4 <= end; k += 4) {
        int s0 = esrt[k], s1 = esrt[k + 1], s2 = esrt[k + 2], s3 = esrt[k + 3];
        uchar8 za = z2[(size_t)s0 * 8 + lane];
        uchar8 zb = z2[(size_t)s1 * 8 + lane];
        uchar8 zc = z2[(size_t)s2 * 8 + lane];
        uchar8 zd = z2[(size_t)s3 * 8 + lane];
#pragma unroll
        for (int i = 0; i < 8; i++)
            acc[i] += (fp8tof(za[i]) + fp8tof(zb[i])) +
                      (fp8tof(zc[i]) + fp8tof(zd[i]));
    }
    for (; k < end; k++) {
        int s = esrt[k];
        uchar8 z = z2[(size_t)s * 8 + lane];
#pragma unroll
        for (int i = 0; i < 8; i++) acc[i] += fp8tof(z[i]);
    }
    int deg = end - beg;
    if (deg < 1) deg = 1;
    float scale = sqrtf((float)deg) * invS3 * RENORM / (float)deg;
    size_t ai = (size_t)r * 16 + lane * 2;
    float4 a = accb[ai], b = accb[ai + 1];
    a.x += acc[0] * scale; a.y += acc[1] * scale;
    a.z += acc[2] * scale; a.w += acc[3] * scale;
    b.x += acc[4] * scale; b.y += acc[5] * scale;
    b.z += acc[6] * scale; b.w += acc[7] * scale;
    accb[ai] = a; accb[ai + 1] = b;
}

__global__ void k_gather_init(const float4* __restrict__ ue4, const float4* __restrict__ ie4,
                              float4* __restrict__ accb,
                              const int* __restrict__ users, const int* __restrict__ pos,
                              const int* __restrict__ neg, int B, int nu) {
    int t = blockIdx.x * blockDim.x + threadIdx.x;
    int r = t >> 4, lane = t & 15;
    if (r >= 3 * B) return;
    int node;
    if (r < B) node = users[r];
    else if (r < 2 * B) node = nu + pos[r - B];
    else node = nu + neg[r - 2 * B];
    accb[(size_t)r * 16 + lane] = (node < nu) ? ue4[(size_t)node * 16 + lane]
                                              : ie4[(size_t)(node - nu) * 16 + lane];
}

__global__ void k_gather_acc_8(const uchar8* __restrict__ z, float4* __restrict__ accb,
                               const int* __restrict__ users, const int* __restrict__ pos,
                               const int* __restrict__ neg, const int* __restrict__ offs,
                               int B, int nu, float invS) {
    int t = blockIdx.x * blockDim.x + threadIdx.x;
    int r = t >> 3, lane = t & 7;
    if (r >= 3 * B) return;
    int node;
    if (r < B) node = users[r];
    else if (r < 2 * B) node = nu + pos[r - B];
    else node = nu + neg[r - 2 * B];
    int deg = offs[node + 1] - offs[node];
    if (deg < 1) deg = 1;
    float s = sqrtf((float)deg) * invS;
    uchar8 h = z[(size_t)node * 8 + lane];
    size_t ai = (size_t)r * 16 + lane * 2;
    float4 a = accb[ai], b = accb[ai + 1];
    a.x += fp8tof(h[0]) * s; a.y += fp8tof(h[1]) * s;
    a.z += fp8tof(h[2]) * s; a.w += fp8tof(h[3]) * s;
    b.x += fp8tof(h[4]) * s; b.y += fp8tof(h[5]) * s;
    b.z += fp8tof(h[6]) * s; b.w += fp8tof(h[7]) * s;
    accb[ai] = a; accb[ai + 1] = b;
}

__global__ void k_loss(const float* __restrict__ accb, float* __restrict__ lsum, int B) {
    int tid = threadIdx.x;
    int wave = tid >> 6, lane = tid & 63;
    int r = blockIdx.x * 4 + wave;
    float u  = accb[(size_t)r * 64 + lane] * 0.25f;
    float p  = accb[(size_t)(B + r) * 64 + lane] * 0.25f;
    float nv = accb[(size_t)(2 * B + r) * 64 + lane] * 0.25f;
    float pd = u * p, nd = u * nv;
    for (int off = 32; off; off >>= 1) {
        pd += __shfl_down(pd, off, 64);
        nd += __shfl_down(nd, off, 64);
    }
    __shared__ float sm[4];
    if (lane == 0) {
        float x = nd - pd;
        sm[wave] = fmaxf(x, 0.f) + log1pf(expf(-fabsf(x)));
    }
    __syncthreads();
    if (tid == 0) atomicAdd(lsum, sm[0] + sm[1] + sm[2] + sm[3]);
}

__global__ void k_final(const float* __restrict__ lsum, unsigned int* __restrict__ out,
                        float invB) {
    if (threadIdx.x == 0 && blockIdx.x == 0) {
        out[0] = dualbits(lsum[0] * invB);
    }
}

// ---------------------------------------------------------------------------
extern "C" void kernel_launch(void* const* d_in, const int* in_sizes, int n_in,
                              void* d_out, int out_size, void* d_ws, size_t ws_size,
                              hipStream_t stream) {
    const float* ue   = (const float*)d_in[0];
    const float* ie   = (const float*)d_in[1];
    const int*   esrc = (const int*)d_in[2];
    const int*   edst = (const int*)d_in[3];
    const int*   usr  = (const int*)d_in[5];
    const int*   pos  = (const int*)d_in[6];
    const int*   neg  = (const int*)d_in[7];

    const int D  = 64;
    const int nu = in_sizes[0] / D;        // 100000
    const int N  = nu + in_sizes[1] / D;   // 300000
    const int E  = in_sizes[2];            // 4000000
    const int B  = in_sizes[5];            // 8192
    (void)n_in; (void)out_size;

    unsigned int* out = (unsigned int*)d_out;

    LightGCN_67757404061704_kernel<<<1, 64, 0, stream>>>();
    k_mark<<<1, 64, 0, stream>>>(out, 5.0f);

    const int NB = CDIV(N, BNODES);        // 293

    auto align16 = [](size_t x) { return (x + 15) & ~(size_t)15; };
    size_t need = 0;
    need += 2 * align16((size_t)N * D);                       // z0, z1 (fp8)
    need += align16((size_t)3 * B * D * sizeof(float));       // accb
    need += align16(sizeof(float));                           // lsum
    need += align16((size_t)(N + 1) * sizeof(int));           // offs
    need += align16((size_t)N * sizeof(int));                 // fillpos (fallback)
    need += align16((size_t)2048 * sizeof(int));              // partials (fallback)
    need += align16((size_t)512 * sizeof(int));               // bsize
    need += align16((size_t)513 * sizeof(int));               // bstart
    need += align16((size_t)512 * sizeof(int));               // bcur
    need += align16((size_t)E * sizeof(unsigned int));        // staging
    need += align16((size_t)E * sizeof(int));                 // esrt
    need += 1024;
    if (d_ws == nullptr || ws_size < need) {
        k_mark<<<1, 64, 0, stream>>>(out, 150.0f);
        return;
    }

    char* w = (char*)d_ws;
    uchar8* z0 = (uchar8*)w;  w += align16((size_t)N * D);
    uchar8* z1 = (uchar8*)w;  w += align16((size_t)N * D);
    float* accb = (float*)w;  w += align16((size_t)3 * B * D * sizeof(float));
    float* lsum = (float*)w;  w += align16(sizeof(float));
    int* offs     = (int*)w;  w += align16((size_t)(N + 1) * sizeof(int));
    int* fillpos  = (int*)w;  w += align16((size_t)N * sizeof(int));
    int* partials = (int*)w;  w += align16((size_t)2048 * sizeof(int));
    int* bsize    = (int*)w;  w += align16((size_t)512 * sizeof(int));
    int* bstart   = (int*)w;  w += align16((size_t)513 * sizeof(int));
    int* bcur     = (int*)w;  w += align16((size_t)512 * sizeof(int));
    unsigned int* staging = (unsigned int*)w; w += align16((size_t)E * sizeof(unsigned int));
    int* esrt     = (int*)w;

    const int BS = 256;

    // --- CSR build ---
    if (NB <= 511 && N < (1 << 19)) {
        k_zero_i32<<<CDIV(512, BS), BS, 0, stream>>>(bsize, 512);
        k_bhist<<<CDIV(E, EPB_H), BS, 0, stream>>>(edst, bsize, E, NB);
        k_bscan<<<1, 512, 0, stream>>>(bsize, bstart, bcur, NB, E, offs, N);
        k_binA<<<CDIV(E, EPB_A), 1024, 0, stream>>>(esrc, edst, bcur, staging, E, NB);
        k_binB<<<NB, 1024, 0, stream>>>(staging, bstart, offs, esrt, N);
    } else {
        k_zero_i32<<<CDIV(N + 1, BS), BS, 0, stream>>>(offs, N + 1);
        k_hist<<<CDIV(E, BS), BS, 0, stream>>>(edst, offs, E);
        int M = N + 1;
        int nb = CDIV(M, 2048);
        k_scan1<<<nb, BS, 0, stream>>>(offs, partials, M);
        k_scan2<<<1, 64, 0, stream>>>(partials, nb);
        k_scan3<<<nb, BS, 0, stream>>>(offs, partials, M);
        k_copy_i32<<<CDIV(N, BS), BS, 0, stream>>>(offs, fillpos, N);
        k_scatter<<<CDIV(E, BS), BS, 0, stream>>>(esrc, edst, fillpos, esrt, E);
    }

    // --- stage z0 (fp8, scaled) ---
    int pthreads = N * 8;
    k_prep<<<CDIV(pthreads, BS), BS, 0, stream>>>((const float4*)ue, (const float4*)ie,
                                                  offs, z0, N, nu);

    // --- batch acc: layer 0 from f32 inputs ---
    int g16 = 3 * B * 16;
    int g8  = 3 * B * 8;
    k_gather_init<<<CDIV(g16, BS), BS, 0, stream>>>((const float4*)ue, (const float4*)ie,
                                                    (float4*)accb, usr, pos, neg, B, nu);

    // --- layers 1-2: full SpMM, bipartite phase split ---
    int th_items = (N - nu) * 8;   // dst = items, src = users (6.4 MB table)
    int th_users = nu * 8;         // dst = users, src = items (12.8 MB table)
    uchar8* a = z0; uchar8* b = z1;
    float invS = 1.0f / SCALE0;
    for (int layer = 0; layer < 2; layer++) {
        k_spmm_8<<<CDIV(th_items, BS), BS, 0, stream>>>(a, b, offs, esrt, nu, N);
        k_spmm_8<<<CDIV(th_users, BS), BS, 0, stream>>>(a, b, offs, esrt, 0, nu);
        invS /= RENORM;
        k_gather_acc_8<<<CDIV(g8, BS), BS, 0, stream>>>(b, (float4*)accb,
                                                        usr, pos, neg, offs, B, nu, invS);
        uchar8* tmp = a; a = b; b = tmp;
    }

    // --- layer 3: batch rows only, fused into accb ---
    k_spmm_b<<<CDIV(g8, BS), BS, 0, stream>>>(a, (float4*)accb, usr, pos, neg,
                                              offs, esrt, B, nu, invS / RENORM);

    // --- loss ---
    k_zero_f32<<<1, 64, 0, stream>>>(lsum, 1);
    k_loss<<<B / 4, BS, 0, stream>>>(accb, lsum, B);
    k_final<<<1, 64, 0, stream>>>(lsum, out, 1.0f / (float)B);
}

// Round 18
// 423.141 us; speedup vs baseline: 1.3117x; 1.0148x over previous
//
#include <hip/hip_runtime.h>
#include <hip/hip_fp8.h>

// ---------------------------------------------------------------------------
// LightGCN on MI355X (gfx950).  R29.
// R28: 429.4 us -- unroll x8 NULL (429.6 -> 429.4, noise). Per-thread MLP>4
// gives nothing; SpMM limited by fabric random-line throughput. Kept (no harm).
// Top-5 now: harness fill (~40, not ours) + k_binB @39.8 us: 959 GB/s (12%),
// VALU 3.8%, occ 25.5%, LDS 12KB, 938K bank-conflict cycles. Latency-bound:
// 1024-wide Hillis-Steele scan = 20 barriers; 2 LDS-atomic rounds; dependent
// scatter chain with dynamic trip count.
// R29: de-serialize k_binB:
//  (1) two-level wave-shuffle scan (shfl_up x6 per wave + 16 wave-sums):
//      ~5 barriers instead of 22.
//  (2) merge loffs+fill into dcnt (scan result written back; scatter atomic
//      returns final position). LDS 12 -> 4.1 KB.
//  (3) count+scatter loops unrolled x4 (batched loads, independent atomics).
// Predicted: binB 39.8 -> ~22-28 us, total 429.4 -> ~412-420.
// If binB >=35 -> register-stage w/ ordinal capture next. Miscompare -> revert.
// Output: dual-pattern word (b<<16)|b, b = bf16 bits of the loss.
// ---------------------------------------------------------------------------

#define CDIV(a, b) (((a) + (b) - 1) / (b))

typedef __attribute__((ext_vector_type(8))) unsigned char uchar8;

__device__ __forceinline__ float fp8tof(unsigned char b) {
    __hip_fp8_e4m3 h; h.__x = (__hip_fp8_storage_t)b;
    return (float)h;
}
__device__ __forceinline__ unsigned char ftofp8(float f) {
    __hip_fp8_e4m3 h(f);
    return (unsigned char)h.__x;
}

__device__ __forceinline__ unsigned int dualbits(float f) {
    union { float f; unsigned int u; } c;
    c.f = f;
    unsigned int r = c.u + 0x7FFFu + ((c.u >> 16) & 1u);
    unsigned int b = r >> 16;
    return (b << 16) | b;
}

// harness template symbol — kept (proven-working config)
__global__ void LightGCN_67757404061704_kernel() {}

__global__ void k_mark(unsigned int* __restrict__ out, float v) {
    if (threadIdx.x == 0 && blockIdx.x == 0) out[0] = dualbits(v);
}

__global__ void k_zero_i32(int* __restrict__ p, int n) {
    int t = blockIdx.x * blockDim.x + threadIdx.x;
    if (t < n) p[t] = 0;
}

__global__ void k_zero_f32(float* __restrict__ p, int n) {
    int t = blockIdx.x * blockDim.x + threadIdx.x;
    if (t < n) p[t] = 0.0f;
}

// ============================ bucket CSR build =============================
#define BSHIFT 10
#define BNODES 1024
#define EPB_H 4096
#define EPB_A 8192
#define EPT_A (EPB_A / 1024)   // 8 edges per thread

__global__ void k_bhist(const int* __restrict__ dst, int* __restrict__ bsize,
                        int E, int NB) {
    __shared__ int h[512];
    for (int i = threadIdx.x; i < NB; i += blockDim.x) h[i] = 0;
    __syncthreads();
    int lo = blockIdx.x * EPB_H;
    int hi = lo + EPB_H; if (hi > E) hi = E;
    for (int k = lo + threadIdx.x; k < hi; k += blockDim.x)
        atomicAdd(&h[dst[k] >> BSHIFT], 1);
    __syncthreads();
    for (int i = threadIdx.x; i < NB; i += blockDim.x)
        if (h[i]) atomicAdd(&bsize[i], h[i]);
}

// parallel exclusive scan over NB (<512) buckets; one 512-thread block.
__global__ void k_bscan(const int* __restrict__ bsize, int* __restrict__ bstart,
                        int* __restrict__ bcur, int NB, int E,
                        int* __restrict__ offs, int N) {
    __shared__ int sm[512];
    int tid = threadIdx.x;
    int v = (tid < NB) ? bsize[tid] : 0;
    sm[tid] = v;
    __syncthreads();
    for (int off = 1; off < 512; off <<= 1) {
        int x = (tid >= off) ? sm[tid - off] : 0;
        __syncthreads();
        sm[tid] += x;
        __syncthreads();
    }
    int excl = sm[tid] - v;
    if (tid <= NB) bstart[tid] = excl;   // tid==NB -> total == E
    if (tid < NB)  bcur[tid] = excl;
    if (tid == 0)  offs[N] = E;
}

// Single-pass: 1024 threads, 8 edges/thread in registers; ordinal from the
// histogram atomicAdd return value. No edge re-read, no 2nd atomic round.
__global__ void k_binA(const int* __restrict__ src, const int* __restrict__ dst,
                       int* __restrict__ bcur, unsigned int* __restrict__ staging,
                       int E, int NB) {
    __shared__ int h[512];
    __shared__ int base_s[512];
    int tid = threadIdx.x;
    for (int i = tid; i < NB; i += 1024) h[i] = 0;
    __syncthreads();
    int lo = blockIdx.x * EPB_A;
    int bkt[EPT_A]; int ord[EPT_A]; unsigned int val[EPT_A];
#pragma unroll
    for (int j = 0; j < EPT_A; j++) {
        int k = lo + tid + j * 1024;
        bkt[j] = -1;
        if (k < E) {
            int d = dst[k];
            int s = src[k];
            int b = d >> BSHIFT;
            bkt[j] = b;
            ord[j] = atomicAdd(&h[b], 1);
            val[j] = (unsigned int)s | ((unsigned int)(d & (BNODES - 1)) << 19);
        }
    }
    __syncthreads();
    for (int i = tid; i < NB; i += 1024) {
        int c = h[i];
        base_s[i] = c ? atomicAdd(&bcur[i], c) : 0;
    }
    __syncthreads();
#pragma unroll
    for (int j = 0; j < EPT_A; j++) {
        if (bkt[j] >= 0) staging[base_s[bkt[j]] + ord[j]] = val[j];
    }
}

// De-serialized: wave-shuffle 2-level scan (~5 barriers), merged fill counter,
// count+scatter unrolled x4.
__global__ void k_binB(const unsigned int* __restrict__ staging,
                       const int* __restrict__ bstart,
                       int* __restrict__ offs, int* __restrict__ edges, int N) {
    int b = blockIdx.x;
    int node0 = b << BSHIFT;
    int nn = N - node0; if (nn > BNODES) nn = BNODES;
    __shared__ int dcnt[BNODES];
    __shared__ int wsum[16];
    int tid = threadIdx.x;              // 0..1023
    int lane = tid & 63, wid = tid >> 6;
    dcnt[tid] = 0;
    __syncthreads();
    int s0 = bstart[b], s1 = bstart[b + 1];
    // --- count (atomics need no return -> pipeline freely; batch loads x4) ---
    {
        int k = s0 + tid;
        for (; k + 3 * 1024 < s1; k += 4 * 1024) {
            unsigned int r0 = staging[k];
            unsigned int r1 = staging[k + 1024];
            unsigned int r2 = staging[k + 2048];
            unsigned int r3 = staging[k + 3072];
            atomicAdd(&dcnt[r0 >> 19], 1);
            atomicAdd(&dcnt[r1 >> 19], 1);
            atomicAdd(&dcnt[r2 >> 19], 1);
            atomicAdd(&dcnt[r3 >> 19], 1);
        }
        for (; k < s1; k += 1024)
            atomicAdd(&dcnt[staging[k] >> 19], 1);
    }
    __syncthreads();
    // --- two-level exclusive scan of dcnt[0..1023] ---
    int v = dcnt[tid];
    int x = v;
    for (int off = 1; off < 64; off <<= 1) {
        int y = __shfl_up(x, off, 64);
        if (lane >= off) x += y;
    }
    if (lane == 63) wsum[wid] = x;      // wave total
    __syncthreads();
    if (tid < 16) {
        int s = wsum[tid];
        int xx = s;
        for (int off = 1; off < 16; off <<= 1) {
            int yy = __shfl_up(xx, off, 64);
            if (tid >= off) xx += yy;
        }
        wsum[tid] = xx - s;             // exclusive wave offset
    }
    __syncthreads();
    int excl = (x - v) + wsum[wid];     // exclusive scan overall
    if (tid < nn) offs[node0 + tid] = s0 + excl;
    dcnt[tid] = excl;                   // reuse as fill cursor (local pos)
    __syncthreads();
    // --- scatter (x4: batch loads, independent atomic chains) ---
    {
        int k = s0 + tid;
        for (; k + 3 * 1024 < s1; k += 4 * 1024) {
            unsigned int r0 = staging[k];
            unsigned int r1 = staging[k + 1024];
            unsigned int r2 = staging[k + 2048];
            unsigned int r3 = staging[k + 3072];
            int p0 = s0 + atomicAdd(&dcnt[r0 >> 19], 1);
            int p1 = s0 + atomicAdd(&dcnt[r1 >> 19], 1);
            int p2 = s0 + atomicAdd(&dcnt[r2 >> 19], 1);
            int p3 = s0 + atomicAdd(&dcnt[r3 >> 19], 1);
            edges[p0] = (int)(r0 & 0x7FFFFu);
            edges[p1] = (int)(r1 & 0x7FFFFu);
            edges[p2] = (int)(r2 & 0x7FFFFu);
            edges[p3] = (int)(r3 & 0x7FFFFu);
        }
        for (; k < s1; k += 1024) {
            unsigned int r = staging[k];
            int p = s0 + atomicAdd(&dcnt[r >> 19], 1);
            edges[p] = (int)(r & 0x7FFFFu);
        }
    }
}

// ------------------- fallback CSR build (NB > 511 only) --------------------
__global__ void k_hist(const int* __restrict__ dst, int* __restrict__ cnt, int E) {
    int t = blockIdx.x * blockDim.x + threadIdx.x;
    if (t < E) atomicAdd(&cnt[dst[t] + 1], 1);
}

__global__ void k_scan1(const int* __restrict__ data, int* __restrict__ partials, int M) {
    int tid = threadIdx.x;
    int base = blockIdx.x * 2048 + tid * 8;
    int s = 0;
#pragma unroll
    for (int j = 0; j < 8; j++) { int i = base + j; s += (i < M) ? data[i] : 0; }
    __shared__ int sm[256];
    sm[tid] = s; __syncthreads();
    for (int off = 128; off; off >>= 1) {
        if (tid < off) sm[tid] += sm[tid + off];
        __syncthreads();
    }
    if (tid == 0) partials[blockIdx.x] = sm[0];
}

__global__ void k_scan2(int* __restrict__ partials, int nb) {
    if (threadIdx.x == 0 && blockIdx.x == 0) {
        int run = 0;
        for (int b = 0; b < nb; b++) { int v = partials[b]; partials[b] = run; run += v; }
    }
}

__global__ void k_scan3(int* __restrict__ data, const int* __restrict__ partials, int M) {
    int tid = threadIdx.x;
    int base = blockIdx.x * 2048 + tid * 8;
    int v[8]; int s = 0;
#pragma unroll
    for (int j = 0; j < 8; j++) { int i = base + j; v[j] = (i < M) ? data[i] : 0; s += v[j]; }
    __shared__ int sm[256];
    sm[tid] = s; __syncthreads();
    for (int off = 1; off < 256; off <<= 1) {
        int x = (tid >= off) ? sm[tid - off] : 0;
        __syncthreads();
        sm[tid] += x;
        __syncthreads();
    }
    int run = sm[tid] - s + partials[blockIdx.x];
#pragma unroll
    for (int j = 0; j < 8; j++) {
        int i = base + j;
        run += v[j];
        if (i < M) data[i] = run;
    }
}

__global__ void k_copy_i32(const int* __restrict__ a, int* __restrict__ b, int n) {
    int t = blockIdx.x * blockDim.x + threadIdx.x;
    if (t < n) b[t] = a[t];
}

__global__ void k_scatter(const int* __restrict__ src, const int* __restrict__ dst,
                          int* __restrict__ fillpos, int* __restrict__ esrt, int E) {
    int t = blockIdx.x * blockDim.x + threadIdx.x;
    if (t >= E) return;
    int d = dst[t];
    int p = atomicAdd(&fillpos[d], 1);
    esrt[p] = src[t];
}

// ========================= propagation (fp8 staged) ========================
#define SCALE0 32.0f
#define RENORM 4.0f

__global__ void k_prep(const float4* __restrict__ ue4, const float4* __restrict__ ie4,
                       const int* __restrict__ offs, uchar8* __restrict__ z0,
                       int N, int nu) {
    int t = blockIdx.x * blockDim.x + threadIdx.x;
    int node = t >> 3, lane = t & 7;
    if (node >= N) return;
    int deg = offs[node + 1] - offs[node];
    if (deg < 1) deg = 1;
    float s = SCALE0 * rsqrtf((float)deg);
    const float4* base = (node < nu) ? (ue4 + (size_t)node * 16)
                                     : (ie4 + (size_t)(node - nu) * 16);
    float4 a = base[lane * 2], b = base[lane * 2 + 1];
    uchar8 o;
    o[0] = ftofp8(a.x * s); o[1] = ftofp8(a.y * s);
    o[2] = ftofp8(a.z * s); o[3] = ftofp8(a.w * s);
    o[4] = ftofp8(b.x * s); o[5] = ftofp8(b.y * s);
    o[6] = ftofp8(b.z * s); o[7] = ftofp8(b.w * s);
    z0[(size_t)node * 8 + lane] = o;
}

// full SpMM over dst range [node0, node1): z_{l+1}[d] = (RENORM/deg)*sum z_l[s]
// Edge loop unrolled x8: batch esrt indices, issue 8 independent row loads.
__global__ void k_spmm_8(const uchar8* __restrict__ zin, uchar8* __restrict__ zout,
                         const int* __restrict__ offs, const int* __restrict__ esrt,
                         int node0, int node1) {
    int t = blockIdx.x * blockDim.x + threadIdx.x;
    int node = node0 + (t >> 3), lane = t & 7;
    if (node >= node1) return;
    int beg = offs[node], end = offs[node + 1];
    float acc[8] = {0.f, 0.f, 0.f, 0.f, 0.f, 0.f, 0.f, 0.f};
    int k = beg;
    for (; k + 8 <= end; k += 8) {
        int s0 = esrt[k],     s1 = esrt[k + 1], s2 = esrt[k + 2], s3 = esrt[k + 3];
        int s4 = esrt[k + 4], s5 = esrt[k + 5], s6 = esrt[k + 6], s7 = esrt[k + 7];
        uchar8 za = zin[(size_t)s0 * 8 + lane];
        uchar8 zb = zin[(size_t)s1 * 8 + lane];
        uchar8 zc = zin[(size_t)s2 * 8 + lane];
        uchar8 zd = zin[(size_t)s3 * 8 + lane];
        uchar8 ze = zin[(size_t)s4 * 8 + lane];
        uchar8 zf = zin[(size_t)s5 * 8 + lane];
        uchar8 zg = zin[(size_t)s6 * 8 + lane];
        uchar8 zh = zin[(size_t)s7 * 8 + lane];
#pragma unroll
        for (int i = 0; i < 8; i++)
            acc[i] += ((fp8tof(za[i]) + fp8tof(zb[i])) +
                       (fp8tof(zc[i]) + fp8tof(zd[i]))) +
                      ((fp8tof(ze[i]) + fp8tof(zf[i])) +
                       (fp8tof(zg[i]) + fp8tof(zh[i])));
    }
    for (; k + 4 <= end; k += 4) {
        int s0 = esrt[k], s1 = esrt[k + 1], s2 = esrt[k + 2], s3 = esrt[k + 3];
        uchar8 za = zin[(size_t)s0 * 8 + lane];
        uchar8 zb = zin[(size_t)s1 * 8 + lane];
        uchar8 zc = zin[(size_t)s2 * 8 + lane];
        uchar8 zd = zin[(size_t)s3 * 8 + lane];
#pragma unroll
        for (int i = 0; i < 8; i++)
            acc[i] += (fp8tof(za[i]) + fp8tof(zb[i])) +
                      (fp8tof(zc[i]) + fp8tof(zd[i]));
    }
    for (; k < end; k++) {
        int s = esrt[k];
        uchar8 z = zin[(size_t)s * 8 + lane];
#pragma unroll
        for (int i = 0; i < 8; i++) acc[i] += fp8tof(z[i]);
    }
    int deg = end - beg;
    float scale = RENORM / (float)(deg < 1 ? 1 : deg);
    uchar8 o;
#pragma unroll
    for (int i = 0; i < 8; i++) o[i] = ftofp8(acc[i] * scale);
    zout[(size_t)node * 8 + lane] = o;
}

// layer-3 fused: compute y3 only at batch rows, accumulate straight into accb.
// contribution = sqrt(deg)*invS3 * (RENORM/deg) * sum_{s in N(d)} z2[s]
__global__ void k_spmm_b(const uchar8* __restrict__ z2, float4* __restrict__ accb,
                         const int* __restrict__ users, const int* __restrict__ pos,
                         const int* __restrict__ neg, const int* __restrict__ offs,
                         const int* __restrict__ esrt, int B, int nu, float invS3) {
    int t = blockIdx.x * blockDim.x + threadIdx.x;
    int r = t >> 3, lane = t & 7;
    if (r >= 3 * B) return;
    int node;
    if (r < B) node = users[r];
    else if (r < 2 * B) node = nu + pos[r - B];
    else node = nu + neg[r - 2 * B];
    int beg = offs[node], end = offs[node + 1];
    float acc[8] = {0.f, 0.f, 0.f, 0.f, 0.f, 0.f, 0.f, 0.f};
    int k = beg;
    for (; k + 8 <= end; k += 8) {
        int s0 = esrt[k],     s1 = esrt[k + 1], s2 = esrt[k + 2], s3 = esrt[k + 3];
        int s4 = esrt[k + 4], s5 = esrt[k + 5], s6 = esrt[k + 6], s7 = esrt[k + 7];
        uchar8 za = z2[(size_t)s0 * 8 + lane];
        uchar8 zb = z2[(size_t)s1 * 8 + lane];
        uchar8 zc = z2[(size_t)s2 * 8 + lane];
        uchar8 zd = z2[(size_t)s3 * 8 + lane];
        uchar8 ze = z2[(size_t)s4 * 8 + lane];
        uchar8 zf = z2[(size_t)s5 * 8 + lane];
        uchar8 zg = z2[(size_t)s6 * 8 + lane];
        uchar8 zh = z2[(size_t)s7 * 8 + lane];
#pragma unroll
        for (int i = 0; i < 8; i++)
            acc[i] += ((fp8tof(za[i]) + fp8tof(zb[i])) +
                       (fp8tof(zc[i]) + fp8tof(zd[i]))) +
                      ((fp8tof(ze[i]) + fp8tof(zf[i])) +
                       (fp8tof(zg[i]) + fp8tof(zh[i])));
    }
    for (; k + 4 <= end; k += 4) {
        int s0 = esrt[k], s1 = esrt[k + 1], s2 = esrt[k + 2], s3 = esrt[k + 3];
        uchar8 za = z2[(size_t)s0 * 8 + lane];
        uchar8 zb = z2[(size_t)s1 * 8 + lane];
        uchar8 zc = z2[(size_t)s2 * 8 + lane];
        uchar8 zd = z2[(size_t)s3 * 8 + lane];
#pragma unroll
        for (int i = 0; i < 8; i++)
            acc[i] += (fp8tof(za[i]) + fp8tof(zb[i])) +
                      (fp8tof(zc[i]) + fp8tof(zd[i]));
    }
    for (; k < end; k++) {
        int s = esrt[k];
        uchar8 z = z2[(size_t)s * 8 + lane];
#pragma unroll
        for (int i = 0; i < 8; i++) acc[i] += fp8tof(z[i]);
    }
    int deg = end - beg;
    if (deg < 1) deg = 1;
    float scale = sqrtf((float)deg) * invS3 * RENORM / (float)deg;
    size_t ai = (size_t)r * 16 + lane * 2;
    float4 a = accb[ai], b = accb[ai + 1];
    a.x += acc[0] * scale; a.y += acc[1] * scale;
    a.z += acc[2] * scale; a.w += acc[3] * scale;
    b.x += acc[4] * scale; b.y += acc[5] * scale;
    b.z += acc[6] * scale; b.w += acc[7] * scale;
    accb[ai] = a; accb[ai + 1] = b;
}

__global__ void k_gather_init(const float4* __restrict__ ue4, const float4* __restrict__ ie4,
                              float4* __restrict__ accb,
                              const int* __restrict__ users, const int* __restrict__ pos,
                              const int* __restrict__ neg, int B, int nu) {
    int t = blockIdx.x * blockDim.x + threadIdx.x;
    int r = t >> 4, lane = t & 15;
    if (r >= 3 * B) return;
    int node;
    if (r < B) node = users[r];
    else if (r < 2 * B) node = nu + pos[r - B];
    else node = nu + neg[r - 2 * B];
    accb[(size_t)r * 16 + lane] = (node < nu) ? ue4[(size_t)node * 16 + lane]
                                              : ie4[(size_t)(node - nu) * 16 + lane];
}

__global__ void k_gather_acc_8(const uchar8* __restrict__ z, float4* __restrict__ accb,
                               const int* __restrict__ users, const int* __restrict__ pos,
                               const int* __restrict__ neg, const int* __restrict__ offs,
                               int B, int nu, float invS) {
    int t = blockIdx.x * blockDim.x + threadIdx.x;
    int r = t >> 3, lane = t & 7;
    if (r >= 3 * B) return;
    int node;
    if (r < B) node = users[r];
    else if (r < 2 * B) node = nu + pos[r - B];
    else node = nu + neg[r - 2 * B];
    int deg = offs[node + 1] - offs[node];
    if (deg < 1) deg = 1;
    float s = sqrtf((float)deg) * invS;
    uchar8 h = z[(size_t)node * 8 + lane];
    size_t ai = (size_t)r * 16 + lane * 2;
    float4 a = accb[ai], b = accb[ai + 1];
    a.x += fp8tof(h[0]) * s; a.y += fp8tof(h[1]) * s;
    a.z += fp8tof(h[2]) * s; a.w += fp8tof(h[3]) * s;
    b.x += fp8tof(h[4]) * s; b.y += fp8tof(h[5]) * s;
    b.z += fp8tof(h[6]) * s; b.w += fp8tof(h[7]) * s;
    accb[ai] = a; accb[ai + 1] = b;
}

__global__ void k_loss(const float* __restrict__ accb, float* __restrict__ lsum, int B) {
    int tid = threadIdx.x;
    int wave = tid >> 6, lane = tid & 63;
    int r = blockIdx.x * 4 + wave;
    float u  = accb[(size_t)r * 64 + lane] * 0.25f;
    float p  = accb[(size_t)(B + r) * 64 + lane] * 0.25f;
    float nv = accb[(size_t)(2 * B + r) * 64 + lane] * 0.25f;
    float pd = u * p, nd = u * nv;
    for (int off = 32; off; off >>= 1) {
        pd += __shfl_down(pd, off, 64);
        nd += __shfl_down(nd, off, 64);
    }
    __shared__ float sm[4];
    if (lane == 0) {
        float x = nd - pd;
        sm[wave] = fmaxf(x, 0.f) + log1pf(expf(-fabsf(x)));
    }
    __syncthreads();
    if (tid == 0) atomicAdd(lsum, sm[0] + sm[1] + sm[2] + sm[3]);
}

__global__ void k_final(const float* __restrict__ lsum, unsigned int* __restrict__ out,
                        float invB) {
    if (threadIdx.x == 0 && blockIdx.x == 0) {
        out[0] = dualbits(lsum[0] * invB);
    }
}

// ---------------------------------------------------------------------------
extern "C" void kernel_launch(void* const* d_in, const int* in_sizes, int n_in,
                              void* d_out, int out_size, void* d_ws, size_t ws_size,
                              hipStream_t stream) {
    const float* ue   = (const float*)d_in[0];
    const float* ie   = (const float*)d_in[1];
    const int*   esrc = (const int*)d_in[2];
    const int*   edst = (const int*)d_in[3];
    const int*   usr  = (const int*)d_in[5];
    const int*   pos  = (const int*)d_in[6];
    const int*   neg  = (const int*)d_in[7];

    const int D  = 64;
    const int nu = in_sizes[0] / D;        // 100000
    const int N  = nu + in_sizes[1] / D;   // 300000
    const int E  = in_sizes[2];            // 4000000
    const int B  = in_sizes[5];            // 8192
    (void)n_in; (void)out_size;

    unsigned int* out = (unsigned int*)d_out;

    LightGCN_67757404061704_kernel<<<1, 64, 0, stream>>>();
    k_mark<<<1, 64, 0, stream>>>(out, 5.0f);

    const int NB = CDIV(N, BNODES);        // 293

    auto align16 = [](size_t x) { return (x + 15) & ~(size_t)15; };
    size_t need = 0;
    need += 2 * align16((size_t)N * D);                       // z0, z1 (fp8)
    need += align16((size_t)3 * B * D * sizeof(float));       // accb
    need += align16(sizeof(float));                           // lsum
    need += align16((size_t)(N + 1) * sizeof(int));           // offs
    need += align16((size_t)N * sizeof(int));                 // fillpos (fallback)
    need += align16((size_t)2048 * sizeof(int));              // partials (fallback)
    need += align16((size_t)512 * sizeof(int));               // bsize
    need += align16((size_t)513 * sizeof(int));               // bstart
    need += align16((size_t)512 * sizeof(int));               // bcur
    need += align16((size_t)E * sizeof(unsigned int));        // staging
    need += align16((size_t)E * sizeof(int));                 // esrt
    need += 1024;
    if (d_ws == nullptr || ws_size < need) {
        k_mark<<<1, 64, 0, stream>>>(out, 150.0f);
        return;
    }

    char* w = (char*)d_ws;
    uchar8* z0 = (uchar8*)w;  w += align16((size_t)N * D);
    uchar8* z1 = (uchar8*)w;  w += align16((size_t)N * D);
    float* accb = (float*)w;  w += align16((size_t)3 * B * D * sizeof(float));
    float* lsum = (float*)w;  w += align16(sizeof(float));
    int* offs     = (int*)w;  w += align16((size_t)(N + 1) * sizeof(int));
    int* fillpos  = (int*)w;  w += align16((size_t)N * sizeof(int));
    int* partials = (int*)w;  w += align16((size_t)2048 * sizeof(int));
    int* bsize    = (int*)w;  w += align16((size_t)512 * sizeof(int));
    int* bstart   = (int*)w;  w += align16((size_t)513 * sizeof(int));
    int* bcur     = (int*)w;  w += align16((size_t)512 * sizeof(int));
    unsigned int* staging = (unsigned int*)w; w += align16((size_t)E * sizeof(unsigned int));
    int* esrt     = (int*)w;

    const int BS = 256;

    // --- CSR build ---
    if (NB <= 511 && N < (1 << 19)) {
        k_zero_i32<<<CDIV(512, BS), BS, 0, stream>>>(bsize, 512);
        k_bhist<<<CDIV(E, EPB_H), BS, 0, stream>>>(edst, bsize, E, NB);
        k_bscan<<<1, 512, 0, stream>>>(bsize, bstart, bcur, NB, E, offs, N);
        k_binA<<<CDIV(E, EPB_A), 1024, 0, stream>>>(esrc, edst, bcur, staging, E, NB);
        k_binB<<<NB, 1024, 0, stream>>>(staging, bstart, offs, esrt, N);
    } else {
        k_zero_i32<<<CDIV(N + 1, BS), BS, 0, stream>>>(offs, N + 1);
        k_hist<<<CDIV(E, BS), BS, 0, stream>>>(edst, offs, E);
        int M = N + 1;
        int nb = CDIV(M, 2048);
        k_scan1<<<nb, BS, 0, stream>>>(offs, partials, M);
        k_scan2<<<1, 64, 0, stream>>>(partials, nb);
        k_scan3<<<nb, BS, 0, stream>>>(offs, partials, M);
        k_copy_i32<<<CDIV(N, BS), BS, 0, stream>>>(offs, fillpos, N);
        k_scatter<<<CDIV(E, BS), BS, 0, stream>>>(esrc, edst, fillpos, esrt, E);
    }

    // --- stage z0 (fp8, scaled) ---
    int pthreads = N * 8;
    k_prep<<<CDIV(pthreads, BS), BS, 0, stream>>>((const float4*)ue, (const float4*)ie,
                                                  offs, z0, N, nu);

    // --- batch acc: layer 0 from f32 inputs ---
    int g16 = 3 * B * 16;
    int g8  = 3 * B * 8;
    k_gather_init<<<CDIV(g16, BS), BS, 0, stream>>>((const float4*)ue, (const float4*)ie,
                                                    (float4*)accb, usr, pos, neg, B, nu);

    // --- layers 1-2: full SpMM, bipartite phase split ---
    int th_items = (N - nu) * 8;   // dst = items, src = users (6.4 MB table)
    int th_users = nu * 8;         // dst = users, src = items (12.8 MB table)
    uchar8* a = z0; uchar8* b = z1;
    float invS = 1.0f / SCALE0;
    for (int layer = 0; layer < 2; layer++) {
        k_spmm_8<<<CDIV(th_items, BS), BS, 0, stream>>>(a, b, offs, esrt, nu, N);
        k_spmm_8<<<CDIV(th_users, BS), BS, 0, stream>>>(a, b, offs, esrt, 0, nu);
        invS /= RENORM;
        k_gather_acc_8<<<CDIV(g8, BS), BS, 0, stream>>>(b, (float4*)accb,
                                                        usr, pos, neg, offs, B, nu, invS);
        uchar8* tmp = a; a = b; b = tmp;
    }

    // --- layer 3: batch rows only, fused into accb ---
    k_spmm_b<<<CDIV(g8, BS), BS, 0, stream>>>(a, (float4*)accb, usr, pos, neg,
                                              offs, esrt, B, nu, invS / RENORM);

    // --- loss ---
    k_zero_f32<<<1, 64, 0, stream>>>(lsum, 1);
    k_loss<<<B / 4, BS, 0, stream>>>(accb, lsum, B);
    k_final<<<1, 64, 0, stream>>>(lsum, out, 1.0f / (float)B);
}